// Round 2
// baseline (254.821 us; speedup 1.0000x reference)
//
#include <hip/hip_runtime.h>

typedef __bf16 v8bf __attribute__((ext_vector_type(8)));
typedef float f32x4 __attribute__((ext_vector_type(4)));
typedef unsigned short u16x8 __attribute__((ext_vector_type(8)));

#define SLEN 256
#define BATCH 256
#define DIM 512
#define SCALE 0.044194173824159216f  // sqrt(1/512)

// fallback-path tile params (round-1 verified kernels)
#define TS 64
#define LDX 520
#define LDB 72
#define KC 64

#define MFMA(a, b, c) __builtin_amdgcn_mfma_f32_16x16x32_bf16((a), (b), (c), 0, 0, 0)

__device__ __forceinline__ unsigned short f2bf(float f) {
  union { float f; unsigned int u; } v; v.f = f;
  unsigned int r = v.u + 0x7FFFu + ((v.u >> 16) & 1u);  // RNE
  return (unsigned short)(r >> 16);
}
__device__ __forceinline__ float bf2f(unsigned short u) {
  union { unsigned int u; float f; } v; v.u = ((unsigned int)u) << 16;
  return v.f;
}
__device__ __forceinline__ v8bf ld8(const unsigned short* p) {
  u16x8 t = *reinterpret_cast<const u16x8*>(p);
  return __builtin_bit_cast(v8bf, t);
}
// async global->LDS, 16B per lane; lds base must be wave-uniform
__device__ __forceinline__ void gload16(const unsigned short* g, unsigned short* l) {
  __builtin_amdgcn_global_load_lds(
      (const __attribute__((address_space(1))) unsigned int*)g,
      (__attribute__((address_space(3))) unsigned int*)l, 16, 0, 0);
}

// ---------- prep: Mt[e][d] = sum_f Wk[f,e]*Wq[f,d]  (= (Wq^T Wk)^T, bf16) ----------
__global__ __launch_bounds__(256) void prep_mt(const float* __restrict__ Wq,
                                               const float* __restrict__ Wk,
                                               unsigned short* __restrict__ Mt) {
  __shared__ float As[32][33];
  __shared__ float Bs[32][33];
  const int e0 = (blockIdx.x & 15) * 32;
  const int d0 = (blockIdx.x >> 4) * 32;
  const int tid = threadIdx.x;
  const int tm = (tid & 15) * 2;
  const int tn = (tid >> 4) * 2;
  const int lf = tid >> 3;
  const int lc = (tid & 7) * 4;
  float a00 = 0.f, a01 = 0.f, a10 = 0.f, a11 = 0.f;
  for (int f0 = 0; f0 < DIM; f0 += 32) {
    __syncthreads();
    const float4 a = *reinterpret_cast<const float4*>(Wk + (size_t)(f0 + lf) * DIM + e0 + lc);
    const float4 b = *reinterpret_cast<const float4*>(Wq + (size_t)(f0 + lf) * DIM + d0 + lc);
    As[lf][lc] = a.x; As[lf][lc + 1] = a.y; As[lf][lc + 2] = a.z; As[lf][lc + 3] = a.w;
    Bs[lf][lc] = b.x; Bs[lf][lc + 1] = b.y; Bs[lf][lc + 2] = b.z; Bs[lf][lc + 3] = b.w;
    __syncthreads();
#pragma unroll
    for (int k = 0; k < 32; ++k) {
      const float x0 = As[k][tm], x1 = As[k][tm + 1];
      const float y0 = Bs[k][tn], y1 = Bs[k][tn + 1];
      a00 += x0 * y0; a01 += x0 * y1; a10 += x1 * y0; a11 += x1 * y1;
    }
  }
  Mt[(size_t)(e0 + tm) * DIM + d0 + tn] = f2bf(a00);
  Mt[(size_t)(e0 + tm) * DIM + d0 + tn + 1] = f2bf(a01);
  Mt[(size_t)(e0 + tm + 1) * DIM + d0 + tn] = f2bf(a10);
  Mt[(size_t)(e0 + tm + 1) * DIM + d0 + tn + 1] = f2bf(a11);
}

// ---------- prep: Wv fp32 -> bf16 ----------
__global__ __launch_bounds__(256) void conv_wv(const float* __restrict__ Wv,
                                               unsigned short* __restrict__ Wvb) {
  const int idx = (blockIdx.x * 256 + threadIdx.x) * 4;
  const float4 v = *reinterpret_cast<const float4*>(Wv + idx);
  uint2 p;
  p.x = (unsigned int)f2bf(v.x) | ((unsigned int)f2bf(v.y) << 16);
  p.y = (unsigned int)f2bf(v.z) | ((unsigned int)f2bf(v.w) << 16);
  *reinterpret_cast<uint2*>(Wvb + idx) = p;
}

// ---------- prep: wkr[d] = sum_f Wk[f,d]*rq[f]  (plain store, no atomics) ----------
__global__ __launch_bounds__(256) void wkr_k2(const float* __restrict__ Wk,
                                              const float* __restrict__ rq,
                                              float* __restrict__ wkr) {
  __shared__ float rqs[DIM];
  const int tid = threadIdx.x;
  rqs[tid] = rq[tid];
  rqs[tid + 256] = rq[tid + 256];
  __syncthreads();
  const int d = blockIdx.x * 256 + tid;
  float s = 0.f;
#pragma unroll 8
  for (int f = 0; f < DIM; ++f) s += Wk[(size_t)f * DIM + d] * rqs[f];
  wkr[d] = s;
}

// ---------- x2b: X[s,b,d] f32 -> Xb[b,s,d] bf16; wdot -> rdpart; xsum partials ----------
__global__ __launch_bounds__(256) void x2b(const float* __restrict__ X,
                                           const float* __restrict__ wkr,
                                           unsigned short* __restrict__ Xb,
                                           float* __restrict__ rdpart,
                                           float* __restrict__ xsump) {
  __shared__ float wp[64][4];
  const int b = blockIdx.x & 255;
  const int sc = blockIdx.x >> 8;  // 0..3
  const int s0 = sc * 64;
  const int tid = threadIdx.x;
  const int lane = tid & 63, wave = tid >> 6;
  const int d0 = 2 * tid;
  const float wk0 = wkr[d0], wk1 = wkr[d0 + 1];
  float xs0 = 0.f, xs1 = 0.f;
#pragma unroll 2
  for (int r = 0; r < 64; ++r) {
    const int s = s0 + r;
    const float2 v = *reinterpret_cast<const float2*>(X + ((size_t)s * BATCH + b) * DIM + d0);
    const unsigned int p = (unsigned int)f2bf(v.x) | ((unsigned int)f2bf(v.y) << 16);
    *reinterpret_cast<unsigned int*>(Xb + ((size_t)b * SLEN + s) * DIM + d0) = p;
    xs0 += v.x; xs1 += v.y;
    float w = wk0 * v.x + wk1 * v.y;
    w += __shfl_xor(w, 1);  w += __shfl_xor(w, 2);  w += __shfl_xor(w, 4);
    w += __shfl_xor(w, 8);  w += __shfl_xor(w, 16); w += __shfl_xor(w, 32);
    if (lane == 0) wp[r][wave] = w;
  }
  __syncthreads();
  if (tid < 64)
    rdpart[(size_t)b * SLEN + s0 + tid] = wp[tid][0] + wp[tid][1] + wp[tid][2] + wp[tid][3];
  const float2 xsv = {xs0, xs1};
  *reinterpret_cast<float2*>(xsump + ((size_t)b * 4 + sc) * DIM + d0) = xsv;
}

// ---------- gemm1: u = Xb @ Mt^T (128x128 tiles); epilogue rdpart[j] += sum_e u[j,e]*x[j,e] ----------
__global__ __launch_bounds__(256, 2) void gemm1(const unsigned short* __restrict__ Xb,
                                                const unsigned short* __restrict__ Mt,
                                                float* __restrict__ rdpart) {
  __shared__ __align__(16) unsigned short As[128 * 64];
  __shared__ __align__(16) unsigned short Bs[128 * 64];
  const int tid = threadIdx.x;
  const int lane = tid & 63, wave = tid >> 6;
  const int wr = wave >> 1, wc = wave & 1;
  const int g = lane >> 4, c = lane & 15;
  // XCD-aware swizzle: 2048 blocks, 8 XCDs; keep the 4 col-tiles of each row-panel on one XCD
  const int work = (blockIdx.x & 7) * 256 + (blockIdx.x >> 3);
  const int rt = work >> 2, ct = work & 3;
  const int j0 = rt * 128;
  const int e0 = ct * 128;

  const int lrow = lane >> 3;         // 0..7
  const int lcol8 = (lane & 7) * 8;   // shorts
  const unsigned short* Ag = Xb + (size_t)(j0 + lrow) * DIM + lcol8;
  const unsigned short* Bg = Mt + (size_t)(e0 + lrow) * DIM + lcol8;

  f32x4 acc[4][4] = {};
  for (int kc = 0; kc < DIM; kc += 64) {
    __syncthreads();
#pragma unroll
    for (int q = 0; q < 4; ++q) {
      const int qq = wave * 4 + q;  // 0..15, 8 rows each
      gload16(Ag + (size_t)(qq * 8) * DIM + kc, &As[qq * 512]);
      gload16(Bg + (size_t)(qq * 8) * DIM + kc, &Bs[qq * 512]);
    }
    __syncthreads();
#pragma unroll
    for (int ks = 0; ks < 64; ks += 32) {
      v8bf a[4], bb[4];
#pragma unroll
      for (int m = 0; m < 4; ++m) a[m] = ld8(&As[(wr * 64 + m * 16 + c) * 64 + ks + 8 * g]);
#pragma unroll
      for (int n = 0; n < 4; ++n) bb[n] = ld8(&Bs[(wc * 64 + n * 16 + c) * 64 + ks + 8 * g]);
#pragma unroll
      for (int m = 0; m < 4; ++m)
#pragma unroll
        for (int n = 0; n < 4; ++n) acc[m][n] = MFMA(a[m], bb[n], acc[m][n]);
    }
  }
  // restage Xb[j0..+128][e0..+128]: first 64 cols into As, second 64 into Bs
  __syncthreads();
#pragma unroll
  for (int q = 0; q < 4; ++q) {
    const int qq = wave * 4 + q;
    gload16(Ag + (size_t)(qq * 8) * DIM + e0, &As[qq * 512]);
    gload16(Ag + (size_t)(qq * 8) * DIM + e0 + 64, &Bs[qq * 512]);
  }
  __syncthreads();
  const unsigned short* xt = (wc == 0) ? As : Bs;
#pragma unroll
  for (int m = 0; m < 4; ++m) {
#pragma unroll
    for (int i = 0; i < 4; ++i) {
      const int r = wr * 64 + m * 16 + 4 * g + i;
      float val = 0.f;
#pragma unroll
      for (int n = 0; n < 4; ++n) val += acc[m][n][i] * bf2f(xt[r * 64 + n * 16 + c]);
      val += __shfl_xor(val, 1); val += __shfl_xor(val, 2);
      val += __shfl_xor(val, 4); val += __shfl_xor(val, 8);
      if (c == 0) atomicAdd(&rdpart[(size_t)j0 + r], val);
    }
  }
}

// ---------- fixup: rd=exp(clip(scale*rdpart)); R; xsum final; xw -> u2 rows ----------
__global__ __launch_bounds__(256) void fixup(const float* __restrict__ rdpart,
                                             const unsigned short* __restrict__ Xb,
                                             const float* __restrict__ xsump,
                                             float* __restrict__ rd, float* __restrict__ Rsum,
                                             float* __restrict__ u2) {
  __shared__ float rds[SLEN];
  __shared__ float wsum[4];
  const int b = blockIdx.x, tid = threadIdx.x;
  float v = rdpart[(size_t)b * SLEN + tid] * SCALE;
  v = fminf(fmaxf(v, -5.0f), 7.0f);
  const float r = expf(v);
  rd[(size_t)b * SLEN + tid] = r;
  rds[tid] = r;
  float t = r;
  t += __shfl_xor(t, 1);  t += __shfl_xor(t, 2);  t += __shfl_xor(t, 4);
  t += __shfl_xor(t, 8);  t += __shfl_xor(t, 16); t += __shfl_xor(t, 32);
  if ((tid & 63) == 0) wsum[tid >> 6] = t;
  __syncthreads();
  if (tid == 0) Rsum[b] = wsum[0] + wsum[1] + wsum[2] + wsum[3];

  const int d0 = 2 * tid;
  float2 xs = {0.f, 0.f};
#pragma unroll
  for (int ch = 0; ch < 4; ++ch) {
    const float2 p = *reinterpret_cast<const float2*>(xsump + ((size_t)b * 4 + ch) * DIM + d0);
    xs.x += p.x; xs.y += p.y;
  }
  float a0 = 0.f, a1 = 0.f;
#pragma unroll 4
  for (int s = 0; s < SLEN; ++s) {
    const unsigned int p =
        *reinterpret_cast<const unsigned int*>(Xb + ((size_t)b * SLEN + s) * DIM + d0);
    const float rr = rds[s];
    a0 += rr * bf2f((unsigned short)(p & 0xffffu));
    a1 += rr * bf2f((unsigned short)(p >> 16));
  }
  *reinterpret_cast<float2*>(u2 + (size_t)b * DIM + d0) = xs;
  const float2 xwv = {a0, a1};
  *reinterpret_cast<float2*>(u2 + (size_t)(BATCH + b) * DIM + d0) = xwv;
}

// ---------- vsvw: c2 = u2 @ Wv^T (f32, 512x512x512) ----------
__global__ __launch_bounds__(256) void vsvw(const float* __restrict__ u2,
                                            const float* __restrict__ Wv,
                                            float* __restrict__ c2) {
  __shared__ float Us[32][33];
  __shared__ float Ws[32][33];
  const int r0 = (blockIdx.x & 15) * 32;
  const int e0 = (blockIdx.x >> 4) * 32;
  const int tid = threadIdx.x;
  const int tm = (tid & 15) * 2;
  const int tn = (tid >> 4) * 2;
  const int lf = tid >> 3;
  const int lc = (tid & 7) * 4;
  float a00 = 0.f, a01 = 0.f, a10 = 0.f, a11 = 0.f;
  for (int k0 = 0; k0 < DIM; k0 += 32) {
    __syncthreads();
    const float4 a = *reinterpret_cast<const float4*>(u2 + (size_t)(r0 + lf) * DIM + k0 + lc);
    const float4 w = *reinterpret_cast<const float4*>(Wv + (size_t)(e0 + lf) * DIM + k0 + lc);
    Us[lf][lc] = a.x; Us[lf][lc + 1] = a.y; Us[lf][lc + 2] = a.z; Us[lf][lc + 3] = a.w;
    Ws[lf][lc] = w.x; Ws[lf][lc + 1] = w.y; Ws[lf][lc + 2] = w.z; Ws[lf][lc + 3] = w.w;
    __syncthreads();
#pragma unroll
    for (int k = 0; k < 32; ++k) {
      const float x0 = Us[tm][k], x1 = Us[tm + 1][k];
      const float y0 = Ws[tn][k], y1 = Ws[tn + 1][k];
      a00 += x0 * y0; a01 += x0 * y1; a10 += x1 * y0; a11 += x1 * y1;
    }
  }
  c2[(size_t)(r0 + tm) * DIM + e0 + tn] = a00;
  c2[(size_t)(r0 + tm) * DIM + e0 + tn + 1] = a01;
  c2[(size_t)(r0 + tm + 1) * DIM + e0 + tn] = a10;
  c2[(size_t)(r0 + tm + 1) * DIM + e0 + tn + 1] = a11;
}

// ---------- gemm2: V = Xb @ Wvb^T; out = alpha*V + beta*vs + gamma*vw ----------
__global__ __launch_bounds__(256, 2) void gemm2(const unsigned short* __restrict__ Xb,
                                                const unsigned short* __restrict__ Wvb,
                                                const float* __restrict__ rd,
                                                const float* __restrict__ Rsum,
                                                const float* __restrict__ c2,
                                                float* __restrict__ out) {
  __shared__ __align__(16) unsigned short As[128 * 64];
  __shared__ __align__(16) unsigned short Bs[128 * 64];
  __shared__ float rds_l[128], vss[128], vws[128];
  const int tid = threadIdx.x;
  const int lane = tid & 63, wave = tid >> 6;
  const int wr = wave >> 1, wc = wave & 1;
  const int g = lane >> 4, c = lane & 15;
  const int work = (blockIdx.x & 7) * 256 + (blockIdx.x >> 3);
  const int rt = work >> 2, ct = work & 3;
  const int j0 = rt * 128;
  const int e0 = ct * 128;
  const int b = j0 >> 8;

  if (tid < 128) {
    rds_l[tid] = rd[(size_t)j0 + tid];
    vss[tid] = c2[(size_t)b * DIM + e0 + tid];
    vws[tid] = c2[(size_t)(BATCH + b) * DIM + e0 + tid];
  }
  const float invR = 1.0f / Rsum[b];
  const float gam = invR * (1.0f / 256.0f);

  const int lrow = lane >> 3;
  const int lcol8 = (lane & 7) * 8;
  const unsigned short* Ag = Xb + (size_t)(j0 + lrow) * DIM + lcol8;
  const unsigned short* Bg = Wvb + (size_t)(e0 + lrow) * DIM + lcol8;

  f32x4 acc[4][4] = {};
  for (int kc = 0; kc < DIM; kc += 64) {
    __syncthreads();
#pragma unroll
    for (int q = 0; q < 4; ++q) {
      const int qq = wave * 4 + q;
      gload16(Ag + (size_t)(qq * 8) * DIM + kc, &As[qq * 512]);
      gload16(Bg + (size_t)(qq * 8) * DIM + kc, &Bs[qq * 512]);
    }
    __syncthreads();
#pragma unroll
    for (int ks = 0; ks < 64; ks += 32) {
      v8bf a[4], bb[4];
#pragma unroll
      for (int m = 0; m < 4; ++m) a[m] = ld8(&As[(wr * 64 + m * 16 + c) * 64 + ks + 8 * g]);
#pragma unroll
      for (int n = 0; n < 4; ++n) bb[n] = ld8(&Bs[(wc * 64 + n * 16 + c) * 64 + ks + 8 * g]);
#pragma unroll
      for (int m = 0; m < 4; ++m)
#pragma unroll
        for (int n = 0; n < 4; ++n) acc[m][n] = MFMA(a[m], bb[n], acc[m][n]);
    }
  }
#pragma unroll
  for (int m = 0; m < 4; ++m) {
#pragma unroll
    for (int i = 0; i < 4; ++i) {
      const int r = wr * 64 + m * 16 + 4 * g + i;
      const float tt = rds_l[r] * invR;
      const float al = tt - 0.00390625f;
      const float be = (1.0f - tt) * 0.00390625f;
      float* orow = out + (size_t)(j0 + r) * DIM + e0;
#pragma unroll
      for (int n = 0; n < 4; ++n) {
        const int cl = wc * 64 + n * 16 + c;
        orow[cl] = al * acc[m][n][i] + be * vss[cl] + gam * vws[cl];
      }
    }
  }
}

// =================== round-1 fallback kernels (verified) ===================
__global__ __launch_bounds__(256, 2) void pass1_fb(
    const float* __restrict__ X, const unsigned short* __restrict__ Mt,
    const float* __restrict__ wkr, float* __restrict__ rd_out,
    float* __restrict__ Rsum, float* __restrict__ xsum, float* __restrict__ xw) {
  __shared__ __align__(16) unsigned short Xs[TS * LDX];
  __shared__ __align__(16) unsigned short Bsh[64 * LDB];
  __shared__ float wkrs[DIM];
  __shared__ float dacc[TS];
  __shared__ float rds[TS];
  const int tid = threadIdx.x;
  const int b = blockIdx.x & 255;
  const int s0 = (blockIdx.x >> 8) * TS;
  const int lane = tid & 63;
  const int wave = tid >> 6;
  const int wr = wave >> 1, wc = wave & 1;
  const int g = lane >> 4, c = lane & 15;
#pragma unroll 4
  for (int r = 0; r < TS; ++r) {
    const float2 v = *reinterpret_cast<const float2*>(
        X + ((size_t)(s0 + r) * BATCH + b) * DIM + tid * 2);
    Xs[r * LDX + tid * 2] = f2bf(v.x);
    Xs[r * LDX + tid * 2 + 1] = f2bf(v.y);
  }
  wkrs[tid] = wkr[tid];
  wkrs[tid + 256] = wkr[tid + 256];
  if (tid < TS) dacc[tid] = 0.f;
  float dp0[4] = {0.f, 0.f, 0.f, 0.f};
  float dp1[4] = {0.f, 0.f, 0.f, 0.f};
  for (int et = 0; et < 8; ++et) {
    const int e0 = et * 64;
    f32x4 acc00 = {0.f,0.f,0.f,0.f}, acc01 = {0.f,0.f,0.f,0.f};
    f32x4 acc10 = {0.f,0.f,0.f,0.f}, acc11 = {0.f,0.f,0.f,0.f};
    for (int kc0 = 0; kc0 < DIM; kc0 += KC) {
      __syncthreads();
      {
        const int e = tid >> 2;
        const int kq = (tid & 3) * 16;
        const uint4* src = reinterpret_cast<const uint4*>(Mt + (size_t)(e0 + e) * DIM + kc0 + kq);
        const uint4 w0 = src[0];
        const uint4 w1 = src[1];
        *reinterpret_cast<uint4*>(&Bsh[e * LDB + kq]) = w0;
        *reinterpret_cast<uint4*>(&Bsh[e * LDB + kq + 8]) = w1;
      }
      __syncthreads();
#pragma unroll
      for (int ks = 0; ks < KC; ks += 32) {
        const int ka = kc0 + ks + 8 * g;
        const int kb = ks + 8 * g;
        const v8bf fa0 = ld8(&Xs[(32 * wr + c) * LDX + ka]);
        const v8bf fa1 = ld8(&Xs[(32 * wr + 16 + c) * LDX + ka]);
        const v8bf fb0 = ld8(&Bsh[(32 * wc + c) * LDB + kb]);
        const v8bf fb1 = ld8(&Bsh[(32 * wc + 16 + c) * LDB + kb]);
        acc00 = MFMA(fa0, fb0, acc00);
        acc01 = MFMA(fa0, fb1, acc01);
        acc10 = MFMA(fa1, fb0, acc10);
        acc11 = MFMA(fa1, fb1, acc11);
      }
    }
#pragma unroll
    for (int i = 0; i < 4; ++i) {
      const int r0 = 32 * wr + 4 * g + i;
      const int ec0 = e0 + 32 * wc + c;
      const float w0 = wkrs[ec0], w1 = wkrs[ec0 + 16];
      dp0[i] += (acc00[i] + w0) * bf2f(Xs[r0 * LDX + ec0]) +
                (acc01[i] + w1) * bf2f(Xs[r0 * LDX + ec0 + 16]);
      dp1[i] += (acc10[i] + w0) * bf2f(Xs[(r0 + 16) * LDX + ec0]) +
                (acc11[i] + w1) * bf2f(Xs[(r0 + 16) * LDX + ec0 + 16]);
    }
  }
#pragma unroll
  for (int i = 0; i < 4; ++i) {
    float v0 = dp0[i], v1 = dp1[i];
    v0 += __shfl_xor(v0, 1); v0 += __shfl_xor(v0, 2);
    v0 += __shfl_xor(v0, 4); v0 += __shfl_xor(v0, 8);
    v1 += __shfl_xor(v1, 1); v1 += __shfl_xor(v1, 2);
    v1 += __shfl_xor(v1, 4); v1 += __shfl_xor(v1, 8);
    if (c == 0) {
      atomicAdd(&dacc[32 * wr + 4 * g + i], v0);
      atomicAdd(&dacc[32 * wr + 16 + 4 * g + i], v1);
    }
  }
  __syncthreads();
  if (tid < TS) {
    float sc = dacc[tid] * SCALE;
    sc = fminf(fmaxf(sc, -5.0f), 7.0f);
    const float r = expf(sc);
    rds[tid] = r;
    rd_out[(size_t)b * SLEN + s0 + tid] = r;
    float t = r;
    t += __shfl_xor(t, 1); t += __shfl_xor(t, 2); t += __shfl_xor(t, 4);
    t += __shfl_xor(t, 8); t += __shfl_xor(t, 16); t += __shfl_xor(t, 32);
    if (tid == 0) atomicAdd(&Rsum[b], t);
  }
  __syncthreads();
#pragma unroll
  for (int dd = 0; dd < 2; ++dd) {
    const int d = tid + dd * 256;
    float s1 = 0.f, s2 = 0.f;
    for (int r = 0; r < TS; ++r) {
      const float xv = bf2f(Xs[r * LDX + d]);
      s1 += xv;
      s2 += rds[r] * xv;
    }
    atomicAdd(&xsum[(size_t)b * DIM + d], s1);
    atomicAdd(&xw[(size_t)b * DIM + d], s2);
  }
}

__global__ __launch_bounds__(256, 2) void pass2_fb(
    const float* __restrict__ X, const unsigned short* __restrict__ Wvb,
    const float* __restrict__ rd, const float* __restrict__ Rsum,
    const float* __restrict__ xsum, const float* __restrict__ xw,
    float* __restrict__ out) {
  __shared__ __align__(16) unsigned short Zs[TS * LDX];
  __shared__ __align__(16) unsigned short Bsh[64 * LDB];
  __shared__ float xss[DIM];
  __shared__ float xws[DIM];
  __shared__ float rds[TS];
  const int tid = threadIdx.x;
  const int b = blockIdx.x & 255;
  const int s0 = (blockIdx.x >> 8) * TS;
  const int lane = tid & 63;
  const int wave = tid >> 6;
  const int wr = wave >> 1, wc = wave & 1;
  const int g = lane >> 4, c = lane & 15;
  xss[tid] = xsum[(size_t)b * DIM + tid];
  xss[tid + 256] = xsum[(size_t)b * DIM + tid + 256];
  xws[tid] = xw[(size_t)b * DIM + tid];
  xws[tid + 256] = xw[(size_t)b * DIM + tid + 256];
  if (tid < TS) rds[tid] = rd[(size_t)b * SLEN + s0 + tid];
  const float Rb = Rsum[b];
  const float invR = 1.0f / Rb;
  const float gam = invR * (1.0f / 256.0f);
  __syncthreads();
#pragma unroll 4
  for (int r = 0; r < TS; ++r) {
    const float rv = rds[r];
    const float al = rv * invR - (1.0f / 256.0f);
    const float be = (1.0f - rv * invR) * (1.0f / 256.0f);
    const float2 v = *reinterpret_cast<const float2*>(
        X + ((size_t)(s0 + r) * BATCH + b) * DIM + tid * 2);
    const int d0 = tid * 2;
    Zs[r * LDX + d0] = f2bf(al * v.x + be * xss[d0] + gam * xws[d0]);
    Zs[r * LDX + d0 + 1] = f2bf(al * v.y + be * xss[d0 + 1] + gam * xws[d0 + 1]);
  }
  const size_t outbase = ((size_t)b * SLEN + s0) * DIM;
  for (int et = 0; et < 8; ++et) {
    const int e0 = et * 64;
    f32x4 acc00 = {0.f,0.f,0.f,0.f}, acc01 = {0.f,0.f,0.f,0.f};
    f32x4 acc10 = {0.f,0.f,0.f,0.f}, acc11 = {0.f,0.f,0.f,0.f};
    for (int kc0 = 0; kc0 < DIM; kc0 += KC) {
      __syncthreads();
      {
        const int e = tid >> 2;
        const int kq = (tid & 3) * 16;
        const uint4* src = reinterpret_cast<const uint4*>(Wvb + (size_t)(e0 + e) * DIM + kc0 + kq);
        const uint4 w0 = src[0];
        const uint4 w1 = src[1];
        *reinterpret_cast<uint4*>(&Bsh[e * LDB + kq]) = w0;
        *reinterpret_cast<uint4*>(&Bsh[e * LDB + kq + 8]) = w1;
      }
      __syncthreads();
#pragma unroll
      for (int ks = 0; ks < KC; ks += 32) {
        const int ka = kc0 + ks + 8 * g;
        const int kb = ks + 8 * g;
        const v8bf fa0 = ld8(&Zs[(32 * wr + c) * LDX + ka]);
        const v8bf fa1 = ld8(&Zs[(32 * wr + 16 + c) * LDX + ka]);
        const v8bf fb0 = ld8(&Bsh[(32 * wc + c) * LDB + kb]);
        const v8bf fb1 = ld8(&Bsh[(32 * wc + 16 + c) * LDB + kb]);
        acc00 = MFMA(fa0, fb0, acc00);
        acc01 = MFMA(fa0, fb1, acc01);
        acc10 = MFMA(fa1, fb0, acc10);
        acc11 = MFMA(fa1, fb1, acc11);
      }
    }
#pragma unroll
    for (int i = 0; i < 4; ++i) {
      const int r0 = 32 * wr + 4 * g + i;
      const int c0 = e0 + 32 * wc + c;
      out[outbase + (size_t)r0 * DIM + c0] = acc00[i];
      out[outbase + (size_t)r0 * DIM + c0 + 16] = acc01[i];
      out[outbase + (size_t)(r0 + 16) * DIM + c0] = acc10[i];
      out[outbase + (size_t)(r0 + 16) * DIM + c0 + 16] = acc11[i];
    }
  }
}

extern "C" void kernel_launch(void* const* d_in, const int* in_sizes, int n_in,
                              void* d_out, int out_size, void* d_ws, size_t ws_size,
                              hipStream_t stream) {
  (void)in_sizes; (void)n_in; (void)out_size;
  const float* X = (const float*)d_in[0];
  const float* Wq = (const float*)d_in[1];
  const float* Wk = (const float*)d_in[2];
  const float* Wv = (const float*)d_in[3];
  const float* rq = (const float*)d_in[4];
  float* out = (float*)d_out;
  char* ws = (char*)d_ws;

  unsigned short* Mt = (unsigned short*)(ws + 0);        // 512 KB
  unsigned short* Wvb = (unsigned short*)(ws + 524288);  // 512 KB

  const size_t NEED = 72884224;  // fast path workspace footprint
  if (ws_size >= NEED) {
    float* wkr = (float*)(ws + 1048576);            // 2 KB
    float* rdpart = (float*)(ws + 1052672);         // 256 KB
    float* rd = (float*)(ws + 1314816);             // 256 KB
    float* Rsum = (float*)(ws + 1576960);           // 4 KB
    float* xsump = (float*)(ws + 1581056);          // 2 MB
    float* u2 = (float*)(ws + 3678208);             // 1 MB
    float* c2 = (float*)(ws + 4726784);             // 1 MB
    unsigned short* Xb = (unsigned short*)(ws + 5775360);  // 64 MB

    prep_mt<<<dim3(256), dim3(256), 0, stream>>>(Wq, Wk, Mt);
    conv_wv<<<dim3(256), dim3(256), 0, stream>>>(Wv, Wvb);
    wkr_k2<<<dim3(2), dim3(256), 0, stream>>>(Wk, rq, wkr);
    x2b<<<dim3(1024), dim3(256), 0, stream>>>(X, wkr, Xb, rdpart, xsump);
    gemm1<<<dim3(2048), dim3(256), 0, stream>>>(Xb, Mt, rdpart);
    fixup<<<dim3(256), dim3(256), 0, stream>>>(rdpart, Xb, xsump, rd, Rsum, u2);
    vsvw<<<dim3(256), dim3(256), 0, stream>>>(u2, Wv, c2);
    gemm2<<<dim3(2048), dim3(256), 0, stream>>>(Xb, Wvb, rd, Rsum, c2, out);
  } else {
    // round-1 verified fallback (needs ~2.4 MB)
    float* rd = (float*)(ws + 1048576);
    float* wkr = (float*)(ws + 1310720);
    float* Rsum = (float*)(ws + 1312768);
    float* xsum = (float*)(ws + 1313792);
    float* xw = (float*)(ws + 1838080);
    hipMemsetAsync(ws + 1310720, 0, 1051648, stream);
    prep_mt<<<dim3(256), dim3(256), 0, stream>>>(Wq, Wk, Mt);
    conv_wv<<<dim3(256), dim3(256), 0, stream>>>(Wv, Wvb);
    wkr_k2<<<dim3(2), dim3(256), 0, stream>>>(Wk, rq, wkr);
    pass1_fb<<<dim3(1024), dim3(256), 0, stream>>>(X, Mt, wkr, rd, Rsum, xsum, xw);
    pass2_fb<<<dim3(1024), dim3(256), 0, stream>>>(X, Wvb, rd, Rsum, xsum, xw, out);
  }
}

// Round 3
// 232.853 us; speedup vs baseline: 1.0943x; 1.0943x over previous
//
#include <hip/hip_runtime.h>

typedef __bf16 v8bf __attribute__((ext_vector_type(8)));
typedef float f32x4 __attribute__((ext_vector_type(4)));
typedef unsigned short u16x8 __attribute__((ext_vector_type(8)));

#define SLEN 256
#define BATCH 256
#define DIM 512
#define SCALE 0.044194173824159216f  // sqrt(1/512)

// fallback-path tile params (round-1 verified kernels)
#define TS 64
#define LDX 520
#define LDB 72
#define KC 64

#define MFMA(a, b, c) __builtin_amdgcn_mfma_f32_16x16x32_bf16((a), (b), (c), 0, 0, 0)

__device__ __forceinline__ unsigned short f2bf(float f) {
  union { float f; unsigned int u; } v; v.f = f;
  unsigned int r = v.u + 0x7FFFu + ((v.u >> 16) & 1u);  // RNE
  return (unsigned short)(r >> 16);
}
__device__ __forceinline__ float bf2f(unsigned short u) {
  union { unsigned int u; float f; } v; v.u = ((unsigned int)u) << 16;
  return v.f;
}
__device__ __forceinline__ v8bf ld8(const unsigned short* p) {
  u16x8 t = *reinterpret_cast<const u16x8*>(p);
  return __builtin_bit_cast(v8bf, t);
}
// async global->LDS, 16B per lane; lds base must be wave-uniform
__device__ __forceinline__ void gload16(const unsigned short* g, unsigned short* l) {
  __builtin_amdgcn_global_load_lds(
      (const __attribute__((address_space(1))) unsigned int*)g,
      (__attribute__((address_space(3))) unsigned int*)l, 16, 0, 0);
}

// ---------- prep: Mt[e][d] = sum_f Wk[f,e]*Wq[f,d]  (= (Wq^T Wk)^T, bf16) ----------
__global__ __launch_bounds__(256) void prep_mt(const float* __restrict__ Wq,
                                               const float* __restrict__ Wk,
                                               unsigned short* __restrict__ Mt) {
  __shared__ float As[32][33];
  __shared__ float Bs[32][33];
  const int e0 = (blockIdx.x & 15) * 32;
  const int d0 = (blockIdx.x >> 4) * 32;
  const int tid = threadIdx.x;
  const int tm = (tid & 15) * 2;
  const int tn = (tid >> 4) * 2;
  const int lf = tid >> 3;
  const int lc = (tid & 7) * 4;
  float a00 = 0.f, a01 = 0.f, a10 = 0.f, a11 = 0.f;
  for (int f0 = 0; f0 < DIM; f0 += 32) {
    __syncthreads();
    const float4 a = *reinterpret_cast<const float4*>(Wk + (size_t)(f0 + lf) * DIM + e0 + lc);
    const float4 b = *reinterpret_cast<const float4*>(Wq + (size_t)(f0 + lf) * DIM + d0 + lc);
    As[lf][lc] = a.x; As[lf][lc + 1] = a.y; As[lf][lc + 2] = a.z; As[lf][lc + 3] = a.w;
    Bs[lf][lc] = b.x; Bs[lf][lc + 1] = b.y; Bs[lf][lc + 2] = b.z; Bs[lf][lc + 3] = b.w;
    __syncthreads();
#pragma unroll
    for (int k = 0; k < 32; ++k) {
      const float x0 = As[k][tm], x1 = As[k][tm + 1];
      const float y0 = Bs[k][tn], y1 = Bs[k][tn + 1];
      a00 += x0 * y0; a01 += x0 * y1; a10 += x1 * y0; a11 += x1 * y1;
    }
  }
  Mt[(size_t)(e0 + tm) * DIM + d0 + tn] = f2bf(a00);
  Mt[(size_t)(e0 + tm) * DIM + d0 + tn + 1] = f2bf(a01);
  Mt[(size_t)(e0 + tm + 1) * DIM + d0 + tn] = f2bf(a10);
  Mt[(size_t)(e0 + tm + 1) * DIM + d0 + tn + 1] = f2bf(a11);
}

// ---------- prep: Wv fp32 -> bf16 ----------
__global__ __launch_bounds__(256) void conv_wv(const float* __restrict__ Wv,
                                               unsigned short* __restrict__ Wvb) {
  const int idx = (blockIdx.x * 256 + threadIdx.x) * 4;
  const float4 v = *reinterpret_cast<const float4*>(Wv + idx);
  uint2 p;
  p.x = (unsigned int)f2bf(v.x) | ((unsigned int)f2bf(v.y) << 16);
  p.y = (unsigned int)f2bf(v.z) | ((unsigned int)f2bf(v.w) << 16);
  *reinterpret_cast<uint2*>(Wvb + idx) = p;
}

// ---------- prep: wkr[d] = sum_f Wk[f,d]*rq[f] ----------
__global__ __launch_bounds__(256) void wkr_k2(const float* __restrict__ Wk,
                                              const float* __restrict__ rq,
                                              float* __restrict__ wkr) {
  __shared__ float rqs[DIM];
  const int tid = threadIdx.x;
  rqs[tid] = rq[tid];
  rqs[tid + 256] = rq[tid + 256];
  __syncthreads();
  const int d = blockIdx.x * 256 + tid;
  float s = 0.f;
#pragma unroll 8
  for (int f = 0; f < DIM; ++f) s += Wk[(size_t)f * DIM + d] * rqs[f];
  wkr[d] = s;
}

// ---------- x2b: X[s,b,d] f32 -> Xb[b,s,d] bf16; per-chunk xsum partials ----------
// Pure streaming: no cross-lane reductions, 8-deep load batching.
__global__ __launch_bounds__(256) void x2b(const float* __restrict__ X,
                                           unsigned short* __restrict__ Xb,
                                           float* __restrict__ xsump) {
  const int b = blockIdx.x & 255;
  const int sc = blockIdx.x >> 8;  // 0..3 (64-row chunk)
  const int s0 = sc * 64;
  const int tid = threadIdx.x;
  const int half = tid >> 7;          // row parity (0/1)
  const int d0 = (tid & 127) * 4;     // 4 floats per thread
  float4 xs = {0.f, 0.f, 0.f, 0.f};
  for (int ib = 0; ib < 32; ib += 8) {
    float4 v[8];
#pragma unroll
    for (int u = 0; u < 8; ++u) {
      const int s = s0 + 2 * (ib + u) + half;
      v[u] = *reinterpret_cast<const float4*>(X + ((size_t)s * BATCH + b) * DIM + d0);
    }
#pragma unroll
    for (int u = 0; u < 8; ++u) {
      const int s = s0 + 2 * (ib + u) + half;
      uint2 p;
      p.x = (unsigned int)f2bf(v[u].x) | ((unsigned int)f2bf(v[u].y) << 16);
      p.y = (unsigned int)f2bf(v[u].z) | ((unsigned int)f2bf(v[u].w) << 16);
      *reinterpret_cast<uint2*>(Xb + ((size_t)b * SLEN + s) * DIM + d0) = p;
      xs.x += v[u].x; xs.y += v[u].y; xs.z += v[u].z; xs.w += v[u].w;
    }
  }
  // per-(chunk,parity) partial: xsump[b][sc*2+half][d0..d0+3]
  *reinterpret_cast<float4*>(xsump + ((size_t)b * 8 + sc * 2 + half) * DIM + d0) = xs;
}

// ---------- gemm1: u = Xb @ Mt^T; epilogue rdpart[j] += sum_e (u[j,e]+wkr[e])*x[j,e] ----------
__global__ __launch_bounds__(256, 2) void gemm1(const unsigned short* __restrict__ Xb,
                                                const unsigned short* __restrict__ Mt,
                                                const float* __restrict__ wkr,
                                                float* __restrict__ rdpart) {
  __shared__ __align__(16) unsigned short As[128 * 64];
  __shared__ __align__(16) unsigned short Bs[128 * 64];
  const int tid = threadIdx.x;
  const int lane = tid & 63, wave = tid >> 6;
  const int wr = wave >> 1, wc = wave & 1;
  const int g = lane >> 4, c = lane & 15;
  const int work = (blockIdx.x & 7) * 256 + (blockIdx.x >> 3);
  const int rt = work >> 2, ct = work & 3;
  const int j0 = rt * 128;
  const int e0 = ct * 128;

  // per-lane wkr values for this block's e-slice
  float wkrl[4];
#pragma unroll
  for (int n = 0; n < 4; ++n) wkrl[n] = wkr[e0 + wc * 64 + n * 16 + c];

  const int lrow = lane >> 3;
  const int lcol8 = (lane & 7) * 8;
  const unsigned short* Ag = Xb + (size_t)(j0 + lrow) * DIM + lcol8;
  const unsigned short* Bg = Mt + (size_t)(e0 + lrow) * DIM + lcol8;

  f32x4 acc[4][4] = {};
  for (int kc = 0; kc < DIM; kc += 64) {
    __syncthreads();
#pragma unroll
    for (int q = 0; q < 4; ++q) {
      const int qq = wave * 4 + q;
      gload16(Ag + (size_t)(qq * 8) * DIM + kc, &As[qq * 512]);
      gload16(Bg + (size_t)(qq * 8) * DIM + kc, &Bs[qq * 512]);
    }
    __syncthreads();
#pragma unroll
    for (int ks = 0; ks < 64; ks += 32) {
      v8bf a[4], bb[4];
#pragma unroll
      for (int m = 0; m < 4; ++m) a[m] = ld8(&As[(wr * 64 + m * 16 + c) * 64 + ks + 8 * g]);
#pragma unroll
      for (int n = 0; n < 4; ++n) bb[n] = ld8(&Bs[(wc * 64 + n * 16 + c) * 64 + ks + 8 * g]);
#pragma unroll
      for (int m = 0; m < 4; ++m)
#pragma unroll
        for (int n = 0; n < 4; ++n) acc[m][n] = MFMA(a[m], bb[n], acc[m][n]);
    }
  }
  // restage Xb[j0..+128][e0..+128]: first 64 cols into As, second 64 into Bs
  __syncthreads();
#pragma unroll
  for (int q = 0; q < 4; ++q) {
    const int qq = wave * 4 + q;
    gload16(Ag + (size_t)(qq * 8) * DIM + e0, &As[qq * 512]);
    gload16(Ag + (size_t)(qq * 8) * DIM + e0 + 64, &Bs[qq * 512]);
  }
  __syncthreads();
  const unsigned short* xt = (wc == 0) ? As : Bs;
#pragma unroll
  for (int m = 0; m < 4; ++m) {
#pragma unroll
    for (int i = 0; i < 4; ++i) {
      const int r = wr * 64 + m * 16 + 4 * g + i;
      float val = 0.f;
#pragma unroll
      for (int n = 0; n < 4; ++n)
        val += (acc[m][n][i] + wkrl[n]) * bf2f(xt[r * 64 + n * 16 + c]);
      val += __shfl_xor(val, 1); val += __shfl_xor(val, 2);
      val += __shfl_xor(val, 4); val += __shfl_xor(val, 8);
      if (c == 0) atomicAdd(&rdpart[(size_t)j0 + r], val);
    }
  }
}

// ---------- fixup1: rd=exp(clip(scale*rdpart)); Rsum; xsum finalize -> u2 rows 0..255 ----------
__global__ __launch_bounds__(256) void fixup1(const float* __restrict__ rdpart,
                                              const float* __restrict__ xsump,
                                              float* __restrict__ rd, float* __restrict__ Rsum,
                                              float* __restrict__ u2) {
  __shared__ float wsum[4];
  const int b = blockIdx.x, tid = threadIdx.x;
  float v = rdpart[(size_t)b * SLEN + tid] * SCALE;
  v = fminf(fmaxf(v, -5.0f), 7.0f);
  const float r = expf(v);
  rd[(size_t)b * SLEN + tid] = r;
  float t = r;
  t += __shfl_xor(t, 1);  t += __shfl_xor(t, 2);  t += __shfl_xor(t, 4);
  t += __shfl_xor(t, 8);  t += __shfl_xor(t, 16); t += __shfl_xor(t, 32);
  if ((tid & 63) == 0) wsum[tid >> 6] = t;
  __syncthreads();
  if (tid == 0) Rsum[b] = wsum[0] + wsum[1] + wsum[2] + wsum[3];

  const int d0 = 2 * tid;
  float2 xs = {0.f, 0.f};
#pragma unroll
  for (int ch = 0; ch < 8; ++ch) {
    const float2 p = *reinterpret_cast<const float2*>(xsump + ((size_t)b * 8 + ch) * DIM + d0);
    xs.x += p.x; xs.y += p.y;
  }
  *reinterpret_cast<float2*>(u2 + (size_t)b * DIM + d0) = xs;
}

// ---------- xwk: u2 row (256+b) += sum_s rd[b,s]*Xb[b,s,:]  (zero-init'd, atomics) ----------
__global__ __launch_bounds__(256) void xwk(const unsigned short* __restrict__ Xb,
                                           const float* __restrict__ rd,
                                           float* __restrict__ u2) {
  __shared__ float rds[64];
  const int b = blockIdx.x & 255;
  const int sc = blockIdx.x >> 8;
  const int s0 = sc * 64;
  const int tid = threadIdx.x;
  if (tid < 64) rds[tid] = rd[(size_t)b * SLEN + s0 + tid];
  __syncthreads();
  const int d0 = 2 * tid;
  float a0 = 0.f, a1 = 0.f;
  for (int rb = 0; rb < 64; rb += 8) {
    unsigned int p[8];
#pragma unroll
    for (int u = 0; u < 8; ++u)
      p[u] = *reinterpret_cast<const unsigned int*>(
          Xb + ((size_t)b * SLEN + s0 + rb + u) * DIM + d0);
#pragma unroll
    for (int u = 0; u < 8; ++u) {
      const float rr = rds[rb + u];
      a0 += rr * bf2f((unsigned short)(p[u] & 0xffffu));
      a1 += rr * bf2f((unsigned short)(p[u] >> 16));
    }
  }
  atomicAdd(&u2[(size_t)(BATCH + b) * DIM + d0], a0);
  atomicAdd(&u2[(size_t)(BATCH + b) * DIM + d0 + 1], a1);
}

// ---------- vsvw: c2 = u2 @ Wv^T (f32, 512x512x512) ----------
__global__ __launch_bounds__(256) void vsvw(const float* __restrict__ u2,
                                            const float* __restrict__ Wv,
                                            float* __restrict__ c2) {
  __shared__ float Us[32][33];
  __shared__ float Ws[32][33];
  const int r0 = (blockIdx.x & 15) * 32;
  const int e0 = (blockIdx.x >> 4) * 32;
  const int tid = threadIdx.x;
  const int tm = (tid & 15) * 2;
  const int tn = (tid >> 4) * 2;
  const int lf = tid >> 3;
  const int lc = (tid & 7) * 4;
  float a00 = 0.f, a01 = 0.f, a10 = 0.f, a11 = 0.f;
  for (int k0 = 0; k0 < DIM; k0 += 32) {
    __syncthreads();
    const float4 a = *reinterpret_cast<const float4*>(u2 + (size_t)(r0 + lf) * DIM + k0 + lc);
    const float4 w = *reinterpret_cast<const float4*>(Wv + (size_t)(e0 + lf) * DIM + k0 + lc);
    Us[lf][lc] = a.x; Us[lf][lc + 1] = a.y; Us[lf][lc + 2] = a.z; Us[lf][lc + 3] = a.w;
    Ws[lf][lc] = w.x; Ws[lf][lc + 1] = w.y; Ws[lf][lc + 2] = w.z; Ws[lf][lc + 3] = w.w;
    __syncthreads();
#pragma unroll
    for (int k = 0; k < 32; ++k) {
      const float x0 = Us[tm][k], x1 = Us[tm + 1][k];
      const float y0 = Ws[tn][k], y1 = Ws[tn + 1][k];
      a00 += x0 * y0; a01 += x0 * y1; a10 += x1 * y0; a11 += x1 * y1;
    }
  }
  c2[(size_t)(r0 + tm) * DIM + e0 + tn] = a00;
  c2[(size_t)(r0 + tm) * DIM + e0 + tn + 1] = a01;
  c2[(size_t)(r0 + tm + 1) * DIM + e0 + tn] = a10;
  c2[(size_t)(r0 + tm + 1) * DIM + e0 + tn + 1] = a11;
}

// ---------- gemm2: V = Xb @ Wvb^T; out = alpha*V + beta*vs + gamma*vw ----------
__global__ __launch_bounds__(256, 2) void gemm2(const unsigned short* __restrict__ Xb,
                                                const unsigned short* __restrict__ Wvb,
                                                const float* __restrict__ rd,
                                                const float* __restrict__ Rsum,
                                                const float* __restrict__ c2,
                                                float* __restrict__ out) {
  __shared__ __align__(16) unsigned short As[128 * 64];
  __shared__ __align__(16) unsigned short Bs[128 * 64];
  __shared__ float rds_l[128], vss[128], vws[128];
  const int tid = threadIdx.x;
  const int lane = tid & 63, wave = tid >> 6;
  const int wr = wave >> 1, wc = wave & 1;
  const int g = lane >> 4, c = lane & 15;
  const int work = (blockIdx.x & 7) * 256 + (blockIdx.x >> 3);
  const int rt = work >> 2, ct = work & 3;
  const int j0 = rt * 128;
  const int e0 = ct * 128;
  const int b = j0 >> 8;

  if (tid < 128) {
    rds_l[tid] = rd[(size_t)j0 + tid];
    vss[tid] = c2[(size_t)b * DIM + e0 + tid];
    vws[tid] = c2[(size_t)(BATCH + b) * DIM + e0 + tid];
  }
  const float invR = 1.0f / Rsum[b];
  const float gam = invR * (1.0f / 256.0f);

  const int lrow = lane >> 3;
  const int lcol8 = (lane & 7) * 8;
  const unsigned short* Ag = Xb + (size_t)(j0 + lrow) * DIM + lcol8;
  const unsigned short* Bg = Wvb + (size_t)(e0 + lrow) * DIM + lcol8;

  f32x4 acc[4][4] = {};
  for (int kc = 0; kc < DIM; kc += 64) {
    __syncthreads();
#pragma unroll
    for (int q = 0; q < 4; ++q) {
      const int qq = wave * 4 + q;
      gload16(Ag + (size_t)(qq * 8) * DIM + kc, &As[qq * 512]);
      gload16(Bg + (size_t)(qq * 8) * DIM + kc, &Bs[qq * 512]);
    }
    __syncthreads();
#pragma unroll
    for (int ks = 0; ks < 64; ks += 32) {
      v8bf a[4], bb[4];
#pragma unroll
      for (int m = 0; m < 4; ++m) a[m] = ld8(&As[(wr * 64 + m * 16 + c) * 64 + ks + 8 * g]);
#pragma unroll
      for (int n = 0; n < 4; ++n) bb[n] = ld8(&Bs[(wc * 64 + n * 16 + c) * 64 + ks + 8 * g]);
#pragma unroll
      for (int m = 0; m < 4; ++m)
#pragma unroll
        for (int n = 0; n < 4; ++n) acc[m][n] = MFMA(a[m], bb[n], acc[m][n]);
    }
  }
#pragma unroll
  for (int m = 0; m < 4; ++m) {
#pragma unroll
    for (int i = 0; i < 4; ++i) {
      const int r = wr * 64 + m * 16 + 4 * g + i;
      const float tt = rds_l[r] * invR;
      const float al = tt - 0.00390625f;
      const float be = (1.0f - tt) * 0.00390625f;
      float* orow = out + (size_t)(j0 + r) * DIM + e0;
#pragma unroll
      for (int n = 0; n < 4; ++n) {
        const int cl = wc * 64 + n * 16 + c;
        orow[cl] = al * acc[m][n][i] + be * vss[cl] + gam * vws[cl];
      }
    }
  }
}

// =================== round-1 fallback kernels (verified) ===================
__global__ __launch_bounds__(256, 2) void pass1_fb(
    const float* __restrict__ X, const unsigned short* __restrict__ Mt,
    const float* __restrict__ wkr, float* __restrict__ rd_out,
    float* __restrict__ Rsum, float* __restrict__ xsum, float* __restrict__ xw) {
  __shared__ __align__(16) unsigned short Xs[TS * LDX];
  __shared__ __align__(16) unsigned short Bsh[64 * LDB];
  __shared__ float wkrs[DIM];
  __shared__ float dacc[TS];
  __shared__ float rds[TS];
  const int tid = threadIdx.x;
  const int b = blockIdx.x & 255;
  const int s0 = (blockIdx.x >> 8) * TS;
  const int lane = tid & 63;
  const int wave = tid >> 6;
  const int wr = wave >> 1, wc = wave & 1;
  const int g = lane >> 4, c = lane & 15;
#pragma unroll 4
  for (int r = 0; r < TS; ++r) {
    const float2 v = *reinterpret_cast<const float2*>(
        X + ((size_t)(s0 + r) * BATCH + b) * DIM + tid * 2);
    Xs[r * LDX + tid * 2] = f2bf(v.x);
    Xs[r * LDX + tid * 2 + 1] = f2bf(v.y);
  }
  wkrs[tid] = wkr[tid];
  wkrs[tid + 256] = wkr[tid + 256];
  if (tid < TS) dacc[tid] = 0.f;
  float dp0[4] = {0.f, 0.f, 0.f, 0.f};
  float dp1[4] = {0.f, 0.f, 0.f, 0.f};
  for (int et = 0; et < 8; ++et) {
    const int e0 = et * 64;
    f32x4 acc00 = {0.f,0.f,0.f,0.f}, acc01 = {0.f,0.f,0.f,0.f};
    f32x4 acc10 = {0.f,0.f,0.f,0.f}, acc11 = {0.f,0.f,0.f,0.f};
    for (int kc0 = 0; kc0 < DIM; kc0 += KC) {
      __syncthreads();
      {
        const int e = tid >> 2;
        const int kq = (tid & 3) * 16;
        const uint4* src = reinterpret_cast<const uint4*>(Mt + (size_t)(e0 + e) * DIM + kc0 + kq);
        const uint4 w0 = src[0];
        const uint4 w1 = src[1];
        *reinterpret_cast<uint4*>(&Bsh[e * LDB + kq]) = w0;
        *reinterpret_cast<uint4*>(&Bsh[e * LDB + kq + 8]) = w1;
      }
      __syncthreads();
#pragma unroll
      for (int ks = 0; ks < KC; ks += 32) {
        const int ka = kc0 + ks + 8 * g;
        const int kb = ks + 8 * g;
        const v8bf fa0 = ld8(&Xs[(32 * wr + c) * LDX + ka]);
        const v8bf fa1 = ld8(&Xs[(32 * wr + 16 + c) * LDX + ka]);
        const v8bf fb0 = ld8(&Bsh[(32 * wc + c) * LDB + kb]);
        const v8bf fb1 = ld8(&Bsh[(32 * wc + 16 + c) * LDB + kb]);
        acc00 = MFMA(fa0, fb0, acc00);
        acc01 = MFMA(fa0, fb1, acc01);
        acc10 = MFMA(fa1, fb0, acc10);
        acc11 = MFMA(fa1, fb1, acc11);
      }
    }
#pragma unroll
    for (int i = 0; i < 4; ++i) {
      const int r0 = 32 * wr + 4 * g + i;
      const int ec0 = e0 + 32 * wc + c;
      const float w0 = wkrs[ec0], w1 = wkrs[ec0 + 16];
      dp0[i] += (acc00[i] + w0) * bf2f(Xs[r0 * LDX + ec0]) +
                (acc01[i] + w1) * bf2f(Xs[r0 * LDX + ec0 + 16]);
      dp1[i] += (acc10[i] + w0) * bf2f(Xs[(r0 + 16) * LDX + ec0]) +
                (acc11[i] + w1) * bf2f(Xs[(r0 + 16) * LDX + ec0 + 16]);
    }
  }
#pragma unroll
  for (int i = 0; i < 4; ++i) {
    float v0 = dp0[i], v1 = dp1[i];
    v0 += __shfl_xor(v0, 1); v0 += __shfl_xor(v0, 2);
    v0 += __shfl_xor(v0, 4); v0 += __shfl_xor(v0, 8);
    v1 += __shfl_xor(v1, 1); v1 += __shfl_xor(v1, 2);
    v1 += __shfl_xor(v1, 4); v1 += __shfl_xor(v1, 8);
    if (c == 0) {
      atomicAdd(&dacc[32 * wr + 4 * g + i], v0);
      atomicAdd(&dacc[32 * wr + 16 + 4 * g + i], v1);
    }
  }
  __syncthreads();
  if (tid < TS) {
    float sc = dacc[tid] * SCALE;
    sc = fminf(fmaxf(sc, -5.0f), 7.0f);
    const float r = expf(sc);
    rds[tid] = r;
    rd_out[(size_t)b * SLEN + s0 + tid] = r;
    float t = r;
    t += __shfl_xor(t, 1); t += __shfl_xor(t, 2); t += __shfl_xor(t, 4);
    t += __shfl_xor(t, 8); t += __shfl_xor(t, 16); t += __shfl_xor(t, 32);
    if (tid == 0) atomicAdd(&Rsum[b], t);
  }
  __syncthreads();
#pragma unroll
  for (int dd = 0; dd < 2; ++dd) {
    const int d = tid + dd * 256;
    float s1 = 0.f, s2 = 0.f;
    for (int r = 0; r < TS; ++r) {
      const float xv = bf2f(Xs[r * LDX + d]);
      s1 += xv;
      s2 += rds[r] * xv;
    }
    atomicAdd(&xsum[(size_t)b * DIM + d], s1);
    atomicAdd(&xw[(size_t)b * DIM + d], s2);
  }
}

__global__ __launch_bounds__(256, 2) void pass2_fb(
    const float* __restrict__ X, const unsigned short* __restrict__ Wvb,
    const float* __restrict__ rd, const float* __restrict__ Rsum,
    const float* __restrict__ xsum, const float* __restrict__ xw,
    float* __restrict__ out) {
  __shared__ __align__(16) unsigned short Zs[TS * LDX];
  __shared__ __align__(16) unsigned short Bsh[64 * LDB];
  __shared__ float xss[DIM];
  __shared__ float xws[DIM];
  __shared__ float rds[TS];
  const int tid = threadIdx.x;
  const int b = blockIdx.x & 255;
  const int s0 = (blockIdx.x >> 8) * TS;
  const int lane = tid & 63;
  const int wave = tid >> 6;
  const int wr = wave >> 1, wc = wave & 1;
  const int g = lane >> 4, c = lane & 15;
  xss[tid] = xsum[(size_t)b * DIM + tid];
  xss[tid + 256] = xsum[(size_t)b * DIM + tid + 256];
  xws[tid] = xw[(size_t)b * DIM + tid];
  xws[tid + 256] = xw[(size_t)b * DIM + tid + 256];
  if (tid < TS) rds[tid] = rd[(size_t)b * SLEN + s0 + tid];
  const float Rb = Rsum[b];
  const float invR = 1.0f / Rb;
  const float gam = invR * (1.0f / 256.0f);
  __syncthreads();
#pragma unroll 4
  for (int r = 0; r < TS; ++r) {
    const float rv = rds[r];
    const float al = rv * invR - (1.0f / 256.0f);
    const float be = (1.0f - rv * invR) * (1.0f / 256.0f);
    const float2 v = *reinterpret_cast<const float2*>(
        X + ((size_t)(s0 + r) * BATCH + b) * DIM + tid * 2);
    const int d0 = tid * 2;
    Zs[r * LDX + d0] = f2bf(al * v.x + be * xss[d0] + gam * xws[d0]);
    Zs[r * LDX + d0 + 1] = f2bf(al * v.y + be * xss[d0 + 1] + gam * xws[d0 + 1]);
  }
  const size_t outbase = ((size_t)b * SLEN + s0) * DIM;
  for (int et = 0; et < 8; ++et) {
    const int e0 = et * 64;
    f32x4 acc00 = {0.f,0.f,0.f,0.f}, acc01 = {0.f,0.f,0.f,0.f};
    f32x4 acc10 = {0.f,0.f,0.f,0.f}, acc11 = {0.f,0.f,0.f,0.f};
    for (int kc0 = 0; kc0 < DIM; kc0 += KC) {
      __syncthreads();
      {
        const int e = tid >> 2;
        const int kq = (tid & 3) * 16;
        const uint4* src = reinterpret_cast<const uint4*>(Wvb + (size_t)(e0 + e) * DIM + kc0 + kq);
        const uint4 w0 = src[0];
        const uint4 w1 = src[1];
        *reinterpret_cast<uint4*>(&Bsh[e * LDB + kq]) = w0;
        *reinterpret_cast<uint4*>(&Bsh[e * LDB + kq + 8]) = w1;
      }
      __syncthreads();
#pragma unroll
      for (int ks = 0; ks < KC; ks += 32) {
        const int ka = kc0 + ks + 8 * g;
        const int kb = ks + 8 * g;
        const v8bf fa0 = ld8(&Zs[(32 * wr + c) * LDX + ka]);
        const v8bf fa1 = ld8(&Zs[(32 * wr + 16 + c) * LDX + ka]);
        const v8bf fb0 = ld8(&Bsh[(32 * wc + c) * LDB + kb]);
        const v8bf fb1 = ld8(&Bsh[(32 * wc + 16 + c) * LDB + kb]);
        acc00 = MFMA(fa0, fb0, acc00);
        acc01 = MFMA(fa0, fb1, acc01);
        acc10 = MFMA(fa1, fb0, acc10);
        acc11 = MFMA(fa1, fb1, acc11);
      }
    }
#pragma unroll
    for (int i = 0; i < 4; ++i) {
      const int r0 = 32 * wr + 4 * g + i;
      const int c0 = e0 + 32 * wc + c;
      out[outbase + (size_t)r0 * DIM + c0] = acc00[i];
      out[outbase + (size_t)r0 * DIM + c0 + 1 - 1] = acc00[i];
      out[outbase + (size_t)r0 * DIM + c0 + 16] = acc01[i];
      out[outbase + (size_t)(r0 + 16) * DIM + c0] = acc10[i];
      out[outbase + (size_t)(r0 + 16) * DIM + c0 + 16] = acc11[i];
    }
  }
}

extern "C" void kernel_launch(void* const* d_in, const int* in_sizes, int n_in,
                              void* d_out, int out_size, void* d_ws, size_t ws_size,
                              hipStream_t stream) {
  (void)in_sizes; (void)n_in; (void)out_size;
  const float* X = (const float*)d_in[0];
  const float* Wq = (const float*)d_in[1];
  const float* Wk = (const float*)d_in[2];
  const float* Wv = (const float*)d_in[3];
  const float* rq = (const float*)d_in[4];
  float* out = (float*)d_out;
  char* ws = (char*)d_ws;

  unsigned short* Mt = (unsigned short*)(ws + 0);        // 512 KB
  unsigned short* Wvb = (unsigned short*)(ws + 524288);  // 512 KB

  const size_t NEED = 74981376;  // fast path workspace footprint
  if (ws_size >= NEED) {
    float* wkr = (float*)(ws + 1048576);            // 2 KB
    float* rdpart = (float*)(ws + 1052672);         // 256 KB (zeroed)
    float* u2 = (float*)(ws + 1314816);             // 1 MB   (zeroed)
    float* c2 = (float*)(ws + 2363392);             // 1 MB
    float* rd = (float*)(ws + 3411968);             // 256 KB
    float* Rsum = (float*)(ws + 3674112);           // 4 KB
    float* xsump = (float*)(ws + 3678208);          // 4 MB
    unsigned short* Xb = (unsigned short*)(ws + 7872512);  // 64 MB

    hipMemsetAsync(ws + 1052672, 0, 1310720, stream);  // rdpart + u2

    prep_mt<<<dim3(256), dim3(256), 0, stream>>>(Wq, Wk, Mt);
    conv_wv<<<dim3(256), dim3(256), 0, stream>>>(Wv, Wvb);
    wkr_k2<<<dim3(2), dim3(256), 0, stream>>>(Wk, rq, wkr);
    x2b<<<dim3(1024), dim3(256), 0, stream>>>(X, Xb, xsump);
    gemm1<<<dim3(2048), dim3(256), 0, stream>>>(Xb, Mt, wkr, rdpart);
    fixup1<<<dim3(256), dim3(256), 0, stream>>>(rdpart, xsump, rd, Rsum, u2);
    xwk<<<dim3(1024), dim3(256), 0, stream>>>(Xb, rd, u2);
    vsvw<<<dim3(256), dim3(256), 0, stream>>>(u2, Wv, c2);
    gemm2<<<dim3(2048), dim3(256), 0, stream>>>(Xb, Wvb, rd, Rsum, c2, out);
  } else {
    // round-1 verified fallback (needs ~2.4 MB)
    float* rd = (float*)(ws + 1048576);
    float* wkr = (float*)(ws + 1310720);
    float* Rsum = (float*)(ws + 1312768);
    float* xsum = (float*)(ws + 1313792);
    float* xw = (float*)(ws + 1838080);
    hipMemsetAsync(ws + 1310720, 0, 1051648, stream);
    prep_mt<<<dim3(256), dim3(256), 0, stream>>>(Wq, Wk, Mt);
    conv_wv<<<dim3(256), dim3(256), 0, stream>>>(Wv, Wvb);
    wkr_k2<<<dim3(2), dim3(256), 0, stream>>>(Wk, rq, wkr);
    pass1_fb<<<dim3(1024), dim3(256), 0, stream>>>(X, Mt, wkr, rd, Rsum, xsum, xw);
    pass2_fb<<<dim3(1024), dim3(256), 0, stream>>>(X, Wvb, rd, Rsum, xsum, xw, out);
  }
}

// Round 4
// 229.999 us; speedup vs baseline: 1.1079x; 1.0124x over previous
//
#include <hip/hip_runtime.h>

typedef __bf16 v8bf __attribute__((ext_vector_type(8)));
typedef float f32x4 __attribute__((ext_vector_type(4)));
typedef unsigned short u16x8 __attribute__((ext_vector_type(8)));

#define SLEN 256
#define BATCH 256
#define DIM 512
#define SCALE 0.044194173824159216f  // sqrt(1/512)

// fallback-path tile params (round-1 verified kernels)
#define TS 64
#define LDX 520
#define LDB 72
#define KC 64

#define MFMA(a, b, c) __builtin_amdgcn_mfma_f32_16x16x32_bf16((a), (b), (c), 0, 0, 0)

__device__ __forceinline__ unsigned short f2bf(float f) {
  union { float f; unsigned int u; } v; v.f = f;
  unsigned int r = v.u + 0x7FFFu + ((v.u >> 16) & 1u);  // RNE
  return (unsigned short)(r >> 16);
}
__device__ __forceinline__ float bf2f(unsigned short u) {
  union { unsigned int u; float f; } v; v.u = ((unsigned int)u) << 16;
  return v.f;
}
__device__ __forceinline__ v8bf ld8(const unsigned short* p) {
  u16x8 t = *reinterpret_cast<const u16x8*>(p);
  return __builtin_bit_cast(v8bf, t);
}
// async global->LDS, 16B per lane; lds base must be wave-uniform
__device__ __forceinline__ void gload16(const unsigned short* g, unsigned short* l) {
  __builtin_amdgcn_global_load_lds(
      (const __attribute__((address_space(1))) unsigned int*)g,
      (__attribute__((address_space(3))) unsigned int*)l, 16, 0, 0);
}

// ---------- zf: fast zero-fill (replaces pathological rocclr fillBufferAligned) ----------
__global__ __launch_bounds__(256) void zf(float4* __restrict__ p, int n4) {
  const int i = blockIdx.x * 256 + threadIdx.x;
  if (i < n4) {
    const float4 z = {0.f, 0.f, 0.f, 0.f};
    p[i] = z;
  }
}

// ---------- prep: Mt[e][d] = sum_f Wk[f,e]*Wq[f,d]  (= (Wq^T Wk)^T, bf16) ----------
__global__ __launch_bounds__(256) void prep_mt(const float* __restrict__ Wq,
                                               const float* __restrict__ Wk,
                                               unsigned short* __restrict__ Mt) {
  __shared__ float As[32][33];
  __shared__ float Bs[32][33];
  const int e0 = (blockIdx.x & 15) * 32;
  const int d0 = (blockIdx.x >> 4) * 32;
  const int tid = threadIdx.x;
  const int tm = (tid & 15) * 2;
  const int tn = (tid >> 4) * 2;
  const int lf = tid >> 3;
  const int lc = (tid & 7) * 4;
  float a00 = 0.f, a01 = 0.f, a10 = 0.f, a11 = 0.f;
  for (int f0 = 0; f0 < DIM; f0 += 32) {
    __syncthreads();
    const float4 a = *reinterpret_cast<const float4*>(Wk + (size_t)(f0 + lf) * DIM + e0 + lc);
    const float4 b = *reinterpret_cast<const float4*>(Wq + (size_t)(f0 + lf) * DIM + d0 + lc);
    As[lf][lc] = a.x; As[lf][lc + 1] = a.y; As[lf][lc + 2] = a.z; As[lf][lc + 3] = a.w;
    Bs[lf][lc] = b.x; Bs[lf][lc + 1] = b.y; Bs[lf][lc + 2] = b.z; Bs[lf][lc + 3] = b.w;
    __syncthreads();
#pragma unroll
    for (int k = 0; k < 32; ++k) {
      const float x0 = As[k][tm], x1 = As[k][tm + 1];
      const float y0 = Bs[k][tn], y1 = Bs[k][tn + 1];
      a00 += x0 * y0; a01 += x0 * y1; a10 += x1 * y0; a11 += x1 * y1;
    }
  }
  Mt[(size_t)(e0 + tm) * DIM + d0 + tn] = f2bf(a00);
  Mt[(size_t)(e0 + tm) * DIM + d0 + tn + 1] = f2bf(a01);
  Mt[(size_t)(e0 + tm + 1) * DIM + d0 + tn] = f2bf(a10);
  Mt[(size_t)(e0 + tm + 1) * DIM + d0 + tn + 1] = f2bf(a11);
}

// ---------- prep: Wv fp32 -> bf16 ----------
__global__ __launch_bounds__(256) void conv_wv(const float* __restrict__ Wv,
                                               unsigned short* __restrict__ Wvb) {
  const int idx = (blockIdx.x * 256 + threadIdx.x) * 4;
  const float4 v = *reinterpret_cast<const float4*>(Wv + idx);
  uint2 p;
  p.x = (unsigned int)f2bf(v.x) | ((unsigned int)f2bf(v.y) << 16);
  p.y = (unsigned int)f2bf(v.z) | ((unsigned int)f2bf(v.w) << 16);
  *reinterpret_cast<uint2*>(Wvb + idx) = p;
}

// ---------- prep: wkr[d] = sum_f Wk[f,d]*rq[f] ----------
__global__ __launch_bounds__(256) void wkr_k2(const float* __restrict__ Wk,
                                              const float* __restrict__ rq,
                                              float* __restrict__ wkr) {
  __shared__ float rqs[DIM];
  const int tid = threadIdx.x;
  rqs[tid] = rq[tid];
  rqs[tid + 256] = rq[tid + 256];
  __syncthreads();
  const int d = blockIdx.x * 256 + tid;
  float s = 0.f;
#pragma unroll 8
  for (int f = 0; f < DIM; ++f) s += Wk[(size_t)f * DIM + d] * rqs[f];
  wkr[d] = s;
}

// ---------- x2b: X[s,b,d] f32 -> Xb[b,s,d] bf16; per-chunk xsum partials ----------
__global__ __launch_bounds__(256) void x2b(const float* __restrict__ X,
                                           unsigned short* __restrict__ Xb,
                                           float* __restrict__ xsump) {
  const int b = blockIdx.x & 255;
  const int sc = blockIdx.x >> 8;  // 0..3 (64-row chunk)
  const int s0 = sc * 64;
  const int tid = threadIdx.x;
  const int half = tid >> 7;          // row parity (0/1)
  const int d0 = (tid & 127) * 4;     // 4 floats per thread
  float4 xs = {0.f, 0.f, 0.f, 0.f};
  for (int ib = 0; ib < 32; ib += 8) {
    float4 v[8];
#pragma unroll
    for (int u = 0; u < 8; ++u) {
      const int s = s0 + 2 * (ib + u) + half;
      v[u] = *reinterpret_cast<const float4*>(X + ((size_t)s * BATCH + b) * DIM + d0);
    }
#pragma unroll
    for (int u = 0; u < 8; ++u) {
      const int s = s0 + 2 * (ib + u) + half;
      uint2 p;
      p.x = (unsigned int)f2bf(v[u].x) | ((unsigned int)f2bf(v[u].y) << 16);
      p.y = (unsigned int)f2bf(v[u].z) | ((unsigned int)f2bf(v[u].w) << 16);
      *reinterpret_cast<uint2*>(Xb + ((size_t)b * SLEN + s) * DIM + d0) = p;
      xs.x += v[u].x; xs.y += v[u].y; xs.z += v[u].z; xs.w += v[u].w;
    }
  }
  *reinterpret_cast<float4*>(xsump + ((size_t)b * 8 + sc * 2 + half) * DIM + d0) = xs;
}

// ---------- gemm1: u = Xb @ Mt^T; epilogue rdpart[j] += sum_e (u[j,e]+wkr[e])*x[j,e] ----------
__global__ __launch_bounds__(256, 2) void gemm1(const unsigned short* __restrict__ Xb,
                                                const unsigned short* __restrict__ Mt,
                                                const float* __restrict__ wkr,
                                                float* __restrict__ rdpart) {
  __shared__ __align__(16) unsigned short As[128 * 64];
  __shared__ __align__(16) unsigned short Bs[128 * 64];
  const int tid = threadIdx.x;
  const int lane = tid & 63, wave = tid >> 6;
  const int wr = wave >> 1, wc = wave & 1;
  const int g = lane >> 4, c = lane & 15;
  const int work = (blockIdx.x & 7) * 256 + (blockIdx.x >> 3);
  const int rt = work >> 2, ct = work & 3;
  const int j0 = rt * 128;
  const int e0 = ct * 128;

  float wkrl[4];
#pragma unroll
  for (int n = 0; n < 4; ++n) wkrl[n] = wkr[e0 + wc * 64 + n * 16 + c];

  const int lrow = lane >> 3;
  const int lcol8 = (lane & 7) * 8;
  const unsigned short* Ag = Xb + (size_t)(j0 + lrow) * DIM + lcol8;
  const unsigned short* Bg = Mt + (size_t)(e0 + lrow) * DIM + lcol8;

  f32x4 acc[4][4] = {};
  for (int kc = 0; kc < DIM; kc += 64) {
    __syncthreads();
#pragma unroll
    for (int q = 0; q < 4; ++q) {
      const int qq = wave * 4 + q;
      gload16(Ag + (size_t)(qq * 8) * DIM + kc, &As[qq * 512]);
      gload16(Bg + (size_t)(qq * 8) * DIM + kc, &Bs[qq * 512]);
    }
    __syncthreads();
#pragma unroll
    for (int ks = 0; ks < 64; ks += 32) {
      v8bf a[4], bb[4];
#pragma unroll
      for (int m = 0; m < 4; ++m) a[m] = ld8(&As[(wr * 64 + m * 16 + c) * 64 + ks + 8 * g]);
#pragma unroll
      for (int n = 0; n < 4; ++n) bb[n] = ld8(&Bs[(wc * 64 + n * 16 + c) * 64 + ks + 8 * g]);
#pragma unroll
      for (int m = 0; m < 4; ++m)
#pragma unroll
        for (int n = 0; n < 4; ++n) acc[m][n] = MFMA(a[m], bb[n], acc[m][n]);
    }
  }
  // restage Xb[j0..+128][e0..+128]: first 64 cols into As, second 64 into Bs
  __syncthreads();
#pragma unroll
  for (int q = 0; q < 4; ++q) {
    const int qq = wave * 4 + q;
    gload16(Ag + (size_t)(qq * 8) * DIM + e0, &As[qq * 512]);
    gload16(Ag + (size_t)(qq * 8) * DIM + e0 + 64, &Bs[qq * 512]);
  }
  __syncthreads();
  const unsigned short* xt = (wc == 0) ? As : Bs;
#pragma unroll
  for (int m = 0; m < 4; ++m) {
#pragma unroll
    for (int i = 0; i < 4; ++i) {
      const int r = wr * 64 + m * 16 + 4 * g + i;
      float val = 0.f;
#pragma unroll
      for (int n = 0; n < 4; ++n)
        val += (acc[m][n][i] + wkrl[n]) * bf2f(xt[r * 64 + n * 16 + c]);
      val += __shfl_xor(val, 1); val += __shfl_xor(val, 2);
      val += __shfl_xor(val, 4); val += __shfl_xor(val, 8);
      if (c == 0) atomicAdd(&rdpart[(size_t)j0 + r], val);
    }
  }
}

// ---------- fixup1: rd=exp(clip(scale*rdpart)); Rsum; xsum finalize -> u2 rows 0..255 ----------
__global__ __launch_bounds__(256) void fixup1(const float* __restrict__ rdpart,
                                              const float* __restrict__ xsump,
                                              float* __restrict__ rd, float* __restrict__ Rsum,
                                              float* __restrict__ u2) {
  __shared__ float wsum[4];
  const int b = blockIdx.x, tid = threadIdx.x;
  float v = rdpart[(size_t)b * SLEN + tid] * SCALE;
  v = fminf(fmaxf(v, -5.0f), 7.0f);
  const float r = expf(v);
  rd[(size_t)b * SLEN + tid] = r;
  float t = r;
  t += __shfl_xor(t, 1);  t += __shfl_xor(t, 2);  t += __shfl_xor(t, 4);
  t += __shfl_xor(t, 8);  t += __shfl_xor(t, 16); t += __shfl_xor(t, 32);
  if ((tid & 63) == 0) wsum[tid >> 6] = t;
  __syncthreads();
  if (tid == 0) Rsum[b] = wsum[0] + wsum[1] + wsum[2] + wsum[3];

  const int d0 = 2 * tid;
  float2 xs = {0.f, 0.f};
#pragma unroll
  for (int ch = 0; ch < 8; ++ch) {
    const float2 p = *reinterpret_cast<const float2*>(xsump + ((size_t)b * 8 + ch) * DIM + d0);
    xs.x += p.x; xs.y += p.y;
  }
  *reinterpret_cast<float2*>(u2 + (size_t)b * DIM + d0) = xs;
}

// ---------- xwk: u2 row (256+b) += sum_s rd[b,s]*Xb[b,s,:]  (zero-init'd, atomics) ----------
__global__ __launch_bounds__(256) void xwk(const unsigned short* __restrict__ Xb,
                                           const float* __restrict__ rd,
                                           float* __restrict__ u2) {
  __shared__ float rds[64];
  const int b = blockIdx.x & 255;
  const int sc = blockIdx.x >> 8;
  const int s0 = sc * 64;
  const int tid = threadIdx.x;
  if (tid < 64) rds[tid] = rd[(size_t)b * SLEN + s0 + tid];
  __syncthreads();
  const int d0 = 2 * tid;
  float a0 = 0.f, a1 = 0.f;
  for (int rb = 0; rb < 64; rb += 8) {
    unsigned int p[8];
#pragma unroll
    for (int u = 0; u < 8; ++u)
      p[u] = *reinterpret_cast<const unsigned int*>(
          Xb + ((size_t)b * SLEN + s0 + rb + u) * DIM + d0);
#pragma unroll
    for (int u = 0; u < 8; ++u) {
      const float rr = rds[rb + u];
      a0 += rr * bf2f((unsigned short)(p[u] & 0xffffu));
      a1 += rr * bf2f((unsigned short)(p[u] >> 16));
    }
  }
  atomicAdd(&u2[(size_t)(BATCH + b) * DIM + d0], a0);
  atomicAdd(&u2[(size_t)(BATCH + b) * DIM + d0 + 1], a1);
}

// ---------- vsvw: c2 = u2 @ Wv^T (f32, 512x512x512) ----------
__global__ __launch_bounds__(256) void vsvw(const float* __restrict__ u2,
                                            const float* __restrict__ Wv,
                                            float* __restrict__ c2) {
  __shared__ float Us[32][33];
  __shared__ float Ws[32][33];
  const int r0 = (blockIdx.x & 15) * 32;
  const int e0 = (blockIdx.x >> 4) * 32;
  const int tid = threadIdx.x;
  const int tm = (tid & 15) * 2;
  const int tn = (tid >> 4) * 2;
  const int lf = tid >> 3;
  const int lc = (tid & 7) * 4;
  float a00 = 0.f, a01 = 0.f, a10 = 0.f, a11 = 0.f;
  for (int k0 = 0; k0 < DIM; k0 += 32) {
    __syncthreads();
    const float4 a = *reinterpret_cast<const float4*>(u2 + (size_t)(r0 + lf) * DIM + k0 + lc);
    const float4 w = *reinterpret_cast<const float4*>(Wv + (size_t)(e0 + lf) * DIM + k0 + lc);
    Us[lf][lc] = a.x; Us[lf][lc + 1] = a.y; Us[lf][lc + 2] = a.z; Us[lf][lc + 3] = a.w;
    Ws[lf][lc] = w.x; Ws[lf][lc + 1] = w.y; Ws[lf][lc + 2] = w.z; Ws[lf][lc + 3] = w.w;
    __syncthreads();
#pragma unroll
    for (int k = 0; k < 32; ++k) {
      const float x0 = Us[tm][k], x1 = Us[tm + 1][k];
      const float y0 = Ws[tn][k], y1 = Ws[tn + 1][k];
      a00 += x0 * y0; a01 += x0 * y1; a10 += x1 * y0; a11 += x1 * y1;
    }
  }
  c2[(size_t)(r0 + tm) * DIM + e0 + tn] = a00;
  c2[(size_t)(r0 + tm) * DIM + e0 + tn + 1] = a01;
  c2[(size_t)(r0 + tm + 1) * DIM + e0 + tn] = a10;
  c2[(size_t)(r0 + tm + 1) * DIM + e0 + tn + 1] = a11;
}

// ---------- gemm2: V = Xb @ Wvb^T; out = alpha*V + beta*vs + gamma*vw ----------
__global__ __launch_bounds__(256, 2) void gemm2(const unsigned short* __restrict__ Xb,
                                                const unsigned short* __restrict__ Wvb,
                                                const float* __restrict__ rd,
                                                const float* __restrict__ Rsum,
                                                const float* __restrict__ c2,
                                                float* __restrict__ out) {
  __shared__ __align__(16) unsigned short As[128 * 64];
  __shared__ __align__(16) unsigned short Bs[128 * 64];
  __shared__ float rds_l[128], vss[128], vws[128];
  const int tid = threadIdx.x;
  const int lane = tid & 63, wave = tid >> 6;
  const int wr = wave >> 1, wc = wave & 1;
  const int g = lane >> 4, c = lane & 15;
  const int work = (blockIdx.x & 7) * 256 + (blockIdx.x >> 3);
  const int rt = work >> 2, ct = work & 3;
  const int j0 = rt * 128;
  const int e0 = ct * 128;
  const int b = j0 >> 8;

  if (tid < 128) {
    rds_l[tid] = rd[(size_t)j0 + tid];
    vss[tid] = c2[(size_t)b * DIM + e0 + tid];
    vws[tid] = c2[(size_t)(BATCH + b) * DIM + e0 + tid];
  }
  const float invR = 1.0f / Rsum[b];
  const float gam = invR * (1.0f / 256.0f);

  const int lrow = lane >> 3;
  const int lcol8 = (lane & 7) * 8;
  const unsigned short* Ag = Xb + (size_t)(j0 + lrow) * DIM + lcol8;
  const unsigned short* Bg = Wvb + (size_t)(e0 + lrow) * DIM + lcol8;

  f32x4 acc[4][4] = {};
  for (int kc = 0; kc < DIM; kc += 64) {
    __syncthreads();
#pragma unroll
    for (int q = 0; q < 4; ++q) {
      const int qq = wave * 4 + q;
      gload16(Ag + (size_t)(qq * 8) * DIM + kc, &As[qq * 512]);
      gload16(Bg + (size_t)(qq * 8) * DIM + kc, &Bs[qq * 512]);
    }
    __syncthreads();
#pragma unroll
    for (int ks = 0; ks < 64; ks += 32) {
      v8bf a[4], bb[4];
#pragma unroll
      for (int m = 0; m < 4; ++m) a[m] = ld8(&As[(wr * 64 + m * 16 + c) * 64 + ks + 8 * g]);
#pragma unroll
      for (int n = 0; n < 4; ++n) bb[n] = ld8(&Bs[(wc * 64 + n * 16 + c) * 64 + ks + 8 * g]);
#pragma unroll
      for (int m = 0; m < 4; ++m)
#pragma unroll
        for (int n = 0; n < 4; ++n) acc[m][n] = MFMA(a[m], bb[n], acc[m][n]);
    }
  }
#pragma unroll
  for (int m = 0; m < 4; ++m) {
#pragma unroll
    for (int i = 0; i < 4; ++i) {
      const int r = wr * 64 + m * 16 + 4 * g + i;
      const float tt = rds_l[r] * invR;
      const float al = tt - 0.00390625f;
      const float be = (1.0f - tt) * 0.00390625f;
      float* orow = out + (size_t)(j0 + r) * DIM + e0;
#pragma unroll
      for (int n = 0; n < 4; ++n) {
        const int cl = wc * 64 + n * 16 + c;
        orow[cl] = al * acc[m][n][i] + be * vss[cl] + gam * vws[cl];
      }
    }
  }
}

// =================== round-1 fallback kernels (verified) ===================
__global__ __launch_bounds__(256, 2) void pass1_fb(
    const float* __restrict__ X, const unsigned short* __restrict__ Mt,
    const float* __restrict__ wkr, float* __restrict__ rd_out,
    float* __restrict__ Rsum, float* __restrict__ xsum, float* __restrict__ xw) {
  __shared__ __align__(16) unsigned short Xs[TS * LDX];
  __shared__ __align__(16) unsigned short Bsh[64 * LDB];
  __shared__ float wkrs[DIM];
  __shared__ float dacc[TS];
  __shared__ float rds[TS];
  const int tid = threadIdx.x;
  const int b = blockIdx.x & 255;
  const int s0 = (blockIdx.x >> 8) * TS;
  const int lane = tid & 63;
  const int wave = tid >> 6;
  const int wr = wave >> 1, wc = wave & 1;
  const int g = lane >> 4, c = lane & 15;
#pragma unroll 4
  for (int r = 0; r < TS; ++r) {
    const float2 v = *reinterpret_cast<const float2*>(
        X + ((size_t)(s0 + r) * BATCH + b) * DIM + tid * 2);
    Xs[r * LDX + tid * 2] = f2bf(v.x);
    Xs[r * LDX + tid * 2 + 1] = f2bf(v.y);
  }
  wkrs[tid] = wkr[tid];
  wkrs[tid + 256] = wkr[tid + 256];
  if (tid < TS) dacc[tid] = 0.f;
  float dp0[4] = {0.f, 0.f, 0.f, 0.f};
  float dp1[4] = {0.f, 0.f, 0.f, 0.f};
  for (int et = 0; et < 8; ++et) {
    const int e0 = et * 64;
    f32x4 acc00 = {0.f,0.f,0.f,0.f}, acc01 = {0.f,0.f,0.f,0.f};
    f32x4 acc10 = {0.f,0.f,0.f,0.f}, acc11 = {0.f,0.f,0.f,0.f};
    for (int kc0 = 0; kc0 < DIM; kc0 += KC) {
      __syncthreads();
      {
        const int e = tid >> 2;
        const int kq = (tid & 3) * 16;
        const uint4* src = reinterpret_cast<const uint4*>(Mt + (size_t)(e0 + e) * DIM + kc0 + kq);
        const uint4 w0 = src[0];
        const uint4 w1 = src[1];
        *reinterpret_cast<uint4*>(&Bsh[e * LDB + kq]) = w0;
        *reinterpret_cast<uint4*>(&Bsh[e * LDB + kq + 8]) = w1;
      }
      __syncthreads();
#pragma unroll
      for (int ks = 0; ks < KC; ks += 32) {
        const int ka = kc0 + ks + 8 * g;
        const int kb = ks + 8 * g;
        const v8bf fa0 = ld8(&Xs[(32 * wr + c) * LDX + ka]);
        const v8bf fa1 = ld8(&Xs[(32 * wr + 16 + c) * LDX + ka]);
        const v8bf fb0 = ld8(&Bsh[(32 * wc + c) * LDB + kb]);
        const v8bf fb1 = ld8(&Bsh[(32 * wc + 16 + c) * LDB + kb]);
        acc00 = MFMA(fa0, fb0, acc00);
        acc01 = MFMA(fa0, fb1, acc01);
        acc10 = MFMA(fa1, fb0, acc10);
        acc11 = MFMA(fa1, fb1, acc11);
      }
    }
#pragma unroll
    for (int i = 0; i < 4; ++i) {
      const int r0 = 32 * wr + 4 * g + i;
      const int ec0 = e0 + 32 * wc + c;
      const float w0 = wkrs[ec0], w1 = wkrs[ec0 + 16];
      dp0[i] += (acc00[i] + w0) * bf2f(Xs[r0 * LDX + ec0]) +
                (acc01[i] + w1) * bf2f(Xs[r0 * LDX + ec0 + 16]);
      dp1[i] += (acc10[i] + w0) * bf2f(Xs[(r0 + 16) * LDX + ec0]) +
                (acc11[i] + w1) * bf2f(Xs[(r0 + 16) * LDX + ec0 + 16]);
    }
  }
#pragma unroll
  for (int i = 0; i < 4; ++i) {
    float v0 = dp0[i], v1 = dp1[i];
    v0 += __shfl_xor(v0, 1); v0 += __shfl_xor(v0, 2);
    v0 += __shfl_xor(v0, 4); v0 += __shfl_xor(v0, 8);
    v1 += __shfl_xor(v1, 1); v1 += __shfl_xor(v1, 2);
    v1 += __shfl_xor(v1, 4); v1 += __shfl_xor(v1, 8);
    if (c == 0) {
      atomicAdd(&dacc[32 * wr + 4 * g + i], v0);
      atomicAdd(&dacc[32 * wr + 16 + 4 * g + i], v1);
    }
  }
  __syncthreads();
  if (tid < TS) {
    float sc = dacc[tid] * SCALE;
    sc = fminf(fmaxf(sc, -5.0f), 7.0f);
    const float r = expf(sc);
    rds[tid] = r;
    rd_out[(size_t)b * SLEN + s0 + tid] = r;
    float t = r;
    t += __shfl_xor(t, 1); t += __shfl_xor(t, 2); t += __shfl_xor(t, 4);
    t += __shfl_xor(t, 8); t += __shfl_xor(t, 16); t += __shfl_xor(t, 32);
    if (tid == 0) atomicAdd(&Rsum[b], t);
  }
  __syncthreads();
#pragma unroll
  for (int dd = 0; dd < 2; ++dd) {
    const int d = tid + dd * 256;
    float s1 = 0.f, s2 = 0.f;
    for (int r = 0; r < TS; ++r) {
      const float xv = bf2f(Xs[r * LDX + d]);
      s1 += xv;
      s2 += rds[r] * xv;
    }
    atomicAdd(&xsum[(size_t)b * DIM + d], s1);
    atomicAdd(&xw[(size_t)b * DIM + d], s2);
  }
}

__global__ __launch_bounds__(256, 2) void pass2_fb(
    const float* __restrict__ X, const unsigned short* __restrict__ Wvb,
    const float* __restrict__ rd, const float* __restrict__ Rsum,
    const float* __restrict__ xsum, const float* __restrict__ xw,
    float* __restrict__ out) {
  __shared__ __align__(16) unsigned short Zs[TS * LDX];
  __shared__ __align__(16) unsigned short Bsh[64 * LDB];
  __shared__ float xss[DIM];
  __shared__ float xws[DIM];
  __shared__ float rds[TS];
  const int tid = threadIdx.x;
  const int b = blockIdx.x & 255;
  const int s0 = (blockIdx.x >> 8) * TS;
  const int lane = tid & 63;
  const int wave = tid >> 6;
  const int wr = wave >> 1, wc = wave & 1;
  const int g = lane >> 4, c = lane & 15;
  xss[tid] = xsum[(size_t)b * DIM + tid];
  xss[tid + 256] = xsum[(size_t)b * DIM + tid + 256];
  xws[tid] = xw[(size_t)b * DIM + tid];
  xws[tid + 256] = xw[(size_t)b * DIM + tid + 256];
  if (tid < TS) rds[tid] = rd[(size_t)b * SLEN + s0 + tid];
  const float Rb = Rsum[b];
  const float invR = 1.0f / Rb;
  const float gam = invR * (1.0f / 256.0f);
  __syncthreads();
#pragma unroll 4
  for (int r = 0; r < TS; ++r) {
    const float rv = rds[r];
    const float al = rv * invR - (1.0f / 256.0f);
    const float be = (1.0f - rv * invR) * (1.0f / 256.0f);
    const float2 v = *reinterpret_cast<const float2*>(
        X + ((size_t)(s0 + r) * BATCH + b) * DIM + tid * 2);
    const int d0 = tid * 2;
    Zs[r * LDX + d0] = f2bf(al * v.x + be * xss[d0] + gam * xws[d0]);
    Zs[r * LDX + d0 + 1] = f2bf(al * v.y + be * xss[d0 + 1] + gam * xws[d0 + 1]);
  }
  const size_t outbase = ((size_t)b * SLEN + s0) * DIM;
  for (int et = 0; et < 8; ++et) {
    const int e0 = et * 64;
    f32x4 acc00 = {0.f,0.f,0.f,0.f}, acc01 = {0.f,0.f,0.f,0.f};
    f32x4 acc10 = {0.f,0.f,0.f,0.f}, acc11 = {0.f,0.f,0.f,0.f};
    for (int kc0 = 0; kc0 < DIM; kc0 += KC) {
      __syncthreads();
      {
        const int e = tid >> 2;
        const int kq = (tid & 3) * 16;
        const uint4* src = reinterpret_cast<const uint4*>(Wvb + (size_t)(e0 + e) * DIM + kc0 + kq);
        const uint4 w0 = src[0];
        const uint4 w1 = src[1];
        *reinterpret_cast<uint4*>(&Bsh[e * LDB + kq]) = w0;
        *reinterpret_cast<uint4*>(&Bsh[e * LDB + kq + 8]) = w1;
      }
      __syncthreads();
#pragma unroll
      for (int ks = 0; ks < KC; ks += 32) {
        const int ka = kc0 + ks + 8 * g;
        const int kb = ks + 8 * g;
        const v8bf fa0 = ld8(&Zs[(32 * wr + c) * LDX + ka]);
        const v8bf fa1 = ld8(&Zs[(32 * wr + 16 + c) * LDX + ka]);
        const v8bf fb0 = ld8(&Bsh[(32 * wc + c) * LDB + kb]);
        const v8bf fb1 = ld8(&Bsh[(32 * wc + 16 + c) * LDB + kb]);
        acc00 = MFMA(fa0, fb0, acc00);
        acc01 = MFMA(fa0, fb1, acc01);
        acc10 = MFMA(fa1, fb0, acc10);
        acc11 = MFMA(fa1, fb1, acc11);
      }
    }
#pragma unroll
    for (int i = 0; i < 4; ++i) {
      const int r0 = 32 * wr + 4 * g + i;
      const int c0 = e0 + 32 * wc + c;
      out[outbase + (size_t)r0 * DIM + c0] = acc00[i];
      out[outbase + (size_t)r0 * DIM + c0 + 16] = acc01[i];
      out[outbase + (size_t)(r0 + 16) * DIM + c0] = acc10[i];
      out[outbase + (size_t)(r0 + 16) * DIM + c0 + 16] = acc11[i];
    }
  }
}

extern "C" void kernel_launch(void* const* d_in, const int* in_sizes, int n_in,
                              void* d_out, int out_size, void* d_ws, size_t ws_size,
                              hipStream_t stream) {
  (void)in_sizes; (void)n_in; (void)out_size;
  const float* X = (const float*)d_in[0];
  const float* Wq = (const float*)d_in[1];
  const float* Wk = (const float*)d_in[2];
  const float* Wv = (const float*)d_in[3];
  const float* rq = (const float*)d_in[4];
  float* out = (float*)d_out;
  char* ws = (char*)d_ws;

  unsigned short* Mt = (unsigned short*)(ws + 0);        // 512 KB
  unsigned short* Wvb = (unsigned short*)(ws + 524288);  // 512 KB

  const size_t NEED = 74981376;  // fast path workspace footprint
  if (ws_size >= NEED) {
    float* wkr = (float*)(ws + 1048576);            // 2 KB
    float* rdpart = (float*)(ws + 1052672);         // 256 KB (zeroed)
    float* u2 = (float*)(ws + 1314816);             // 1 MB   (zeroed)
    float* c2 = (float*)(ws + 2363392);             // 1 MB
    float* rd = (float*)(ws + 3411968);             // 256 KB
    float* Rsum = (float*)(ws + 3674112);           // 4 KB
    float* xsump = (float*)(ws + 3678208);          // 4 MB
    unsigned short* Xb = (unsigned short*)(ws + 7872512);  // 64 MB

    // zero rdpart + u2 with our own fill (rocclr's small fillBufferAligned
    // kernel measured 75-77us at 17 GB/s for this 1.28 MB region)
    zf<<<dim3(320), dim3(256), 0, stream>>>((float4*)(ws + 1052672), 81920);

    prep_mt<<<dim3(256), dim3(256), 0, stream>>>(Wq, Wk, Mt);
    conv_wv<<<dim3(256), dim3(256), 0, stream>>>(Wv, Wvb);
    wkr_k2<<<dim3(2), dim3(256), 0, stream>>>(Wk, rq, wkr);
    x2b<<<dim3(1024), dim3(256), 0, stream>>>(X, Xb, xsump);
    gemm1<<<dim3(2048), dim3(256), 0, stream>>>(Xb, Mt, wkr, rdpart);
    fixup1<<<dim3(256), dim3(256), 0, stream>>>(rdpart, xsump, rd, Rsum, u2);
    xwk<<<dim3(1024), dim3(256), 0, stream>>>(Xb, rd, u2);
    vsvw<<<dim3(256), dim3(256), 0, stream>>>(u2, Wv, c2);
    gemm2<<<dim3(2048), dim3(256), 0, stream>>>(Xb, Wvb, rd, Rsum, c2, out);
  } else {
    // round-1 verified fallback (needs ~2.4 MB)
    float* rd = (float*)(ws + 1048576);
    float* wkr = (float*)(ws + 1310720);
    float* Rsum = (float*)(ws + 1312768);
    float* xsum = (float*)(ws + 1313792);
    float* xw = (float*)(ws + 1838080);
    zf<<<dim3(257), dim3(256), 0, stream>>>((float4*)(ws + 1310720), 65728);
    prep_mt<<<dim3(256), dim3(256), 0, stream>>>(Wq, Wk, Mt);
    conv_wv<<<dim3(256), dim3(256), 0, stream>>>(Wv, Wvb);
    wkr_k2<<<dim3(2), dim3(256), 0, stream>>>(Wk, rq, wkr);
    pass1_fb<<<dim3(1024), dim3(256), 0, stream>>>(X, Mt, wkr, rd, Rsum, xsum, xw);
    pass2_fb<<<dim3(1024), dim3(256), 0, stream>>>(X, Wvb, rd, Rsum, xsum, xw, out);
  }
}

// Round 5
// 223.377 us; speedup vs baseline: 1.1408x; 1.0296x over previous
//
#include <hip/hip_runtime.h>

typedef __bf16 v8bf __attribute__((ext_vector_type(8)));
typedef float f32x4 __attribute__((ext_vector_type(4)));
typedef unsigned short u16x8 __attribute__((ext_vector_type(8)));

#define SLEN 256
#define BATCH 256
#define DIM 512
#define SCALE 0.044194173824159216f  // sqrt(1/512)

// fallback-path tile params (round-1 verified kernels)
#define TS 64
#define LDX 520
#define LDB 72
#define KC 64

#define MFMA(a, b, c) __builtin_amdgcn_mfma_f32_16x16x32_bf16((a), (b), (c), 0, 0, 0)

__device__ __forceinline__ unsigned short f2bf(float f) {
  union { float f; unsigned int u; } v; v.f = f;
  unsigned int r = v.u + 0x7FFFu + ((v.u >> 16) & 1u);  // RNE
  return (unsigned short)(r >> 16);
}
__device__ __forceinline__ float bf2f(unsigned short u) {
  union { unsigned int u; float f; } v; v.u = ((unsigned int)u) << 16;
  return v.f;
}
__device__ __forceinline__ v8bf ld8(const unsigned short* p) {
  u16x8 t = *reinterpret_cast<const u16x8*>(p);
  return __builtin_bit_cast(v8bf, t);
}
// async global->LDS, 16B per lane; lds base must be wave-uniform
__device__ __forceinline__ void gload16(const unsigned short* g, unsigned short* l) {
  __builtin_amdgcn_global_load_lds(
      (const __attribute__((address_space(1))) unsigned int*)g,
      (__attribute__((address_space(3))) unsigned int*)l, 16, 0, 0);
}

// ---------- zf: fast zero-fill ----------
__global__ __launch_bounds__(256) void zf(float4* __restrict__ p, int n4) {
  const int i = blockIdx.x * 256 + threadIdx.x;
  if (i < n4) {
    const float4 z = {0.f, 0.f, 0.f, 0.f};
    p[i] = z;
  }
}

// ---------- prep: Mt[e][d] = sum_f Wk[f,e]*Wq[f,d]  (= (Wq^T Wk)^T, bf16) ----------
__global__ __launch_bounds__(256) void prep_mt(const float* __restrict__ Wq,
                                               const float* __restrict__ Wk,
                                               unsigned short* __restrict__ Mt) {
  __shared__ float As[32][33];
  __shared__ float Bs[32][33];
  const int e0 = (blockIdx.x & 15) * 32;
  const int d0 = (blockIdx.x >> 4) * 32;
  const int tid = threadIdx.x;
  const int tm = (tid & 15) * 2;
  const int tn = (tid >> 4) * 2;
  const int lf = tid >> 3;
  const int lc = (tid & 7) * 4;
  float a00 = 0.f, a01 = 0.f, a10 = 0.f, a11 = 0.f;
  for (int f0 = 0; f0 < DIM; f0 += 32) {
    __syncthreads();
    const float4 a = *reinterpret_cast<const float4*>(Wk + (size_t)(f0 + lf) * DIM + e0 + lc);
    const float4 b = *reinterpret_cast<const float4*>(Wq + (size_t)(f0 + lf) * DIM + d0 + lc);
    As[lf][lc] = a.x; As[lf][lc + 1] = a.y; As[lf][lc + 2] = a.z; As[lf][lc + 3] = a.w;
    Bs[lf][lc] = b.x; Bs[lf][lc + 1] = b.y; Bs[lf][lc + 2] = b.z; Bs[lf][lc + 3] = b.w;
    __syncthreads();
#pragma unroll
    for (int k = 0; k < 32; ++k) {
      const float x0 = As[k][tm], x1 = As[k][tm + 1];
      const float y0 = Bs[k][tn], y1 = Bs[k][tn + 1];
      a00 += x0 * y0; a01 += x0 * y1; a10 += x1 * y0; a11 += x1 * y1;
    }
  }
  Mt[(size_t)(e0 + tm) * DIM + d0 + tn] = f2bf(a00);
  Mt[(size_t)(e0 + tm) * DIM + d0 + tn + 1] = f2bf(a01);
  Mt[(size_t)(e0 + tm + 1) * DIM + d0 + tn] = f2bf(a10);
  Mt[(size_t)(e0 + tm + 1) * DIM + d0 + tn + 1] = f2bf(a11);
}

// ---------- prep: Wv fp32 -> bf16 ----------
__global__ __launch_bounds__(256) void conv_wv(const float* __restrict__ Wv,
                                               unsigned short* __restrict__ Wvb) {
  const int idx = (blockIdx.x * 256 + threadIdx.x) * 4;
  const float4 v = *reinterpret_cast<const float4*>(Wv + idx);
  uint2 p;
  p.x = (unsigned int)f2bf(v.x) | ((unsigned int)f2bf(v.y) << 16);
  p.y = (unsigned int)f2bf(v.z) | ((unsigned int)f2bf(v.w) << 16);
  *reinterpret_cast<uint2*>(Wvb + idx) = p;
}

// ---------- prep: wkr[d] += partial over 32 f rows (wkr zeroed by zf) ----------
__global__ __launch_bounds__(256) void wkr_k3(const float* __restrict__ Wk,
                                              const float* __restrict__ rq,
                                              float* __restrict__ wkr) {
  const int f0 = blockIdx.x * 32;
  const int d = threadIdx.x;
  float s1 = 0.f, s2 = 0.f;
#pragma unroll
  for (int f = f0; f < f0 + 32; ++f) {
    const float r = rq[f];
    s1 += Wk[(size_t)f * DIM + d] * r;
    s2 += Wk[(size_t)f * DIM + d + 256] * r;
  }
  atomicAdd(&wkr[d], s1);
  atomicAdd(&wkr[d + 256], s2);
}

// ---------- prep: wkr (fallback path, plain store) ----------
__global__ __launch_bounds__(256) void wkr_k2(const float* __restrict__ Wk,
                                              const float* __restrict__ rq,
                                              float* __restrict__ wkr) {
  __shared__ float rqs[DIM];
  const int tid = threadIdx.x;
  rqs[tid] = rq[tid];
  rqs[tid + 256] = rq[tid + 256];
  __syncthreads();
  const int d = blockIdx.x * 256 + tid;
  float s = 0.f;
#pragma unroll 8
  for (int f = 0; f < DIM; ++f) s += Wk[(size_t)f * DIM + d] * rqs[f];
  wkr[d] = s;
}

// ---------- x2b: X[s,b,d] f32 -> Xb[b,s,d] bf16; per-chunk xsum partials ----------
__global__ __launch_bounds__(256) void x2b(const float* __restrict__ X,
                                           unsigned short* __restrict__ Xb,
                                           float* __restrict__ xsump) {
  const int b = blockIdx.x & 255;
  const int sc = blockIdx.x >> 8;  // 0..3 (64-row chunk)
  const int s0 = sc * 64;
  const int tid = threadIdx.x;
  const int half = tid >> 7;
  const int d0 = (tid & 127) * 4;
  float4 xs = {0.f, 0.f, 0.f, 0.f};
  for (int ib = 0; ib < 32; ib += 8) {
    float4 v[8];
#pragma unroll
    for (int u = 0; u < 8; ++u) {
      const int s = s0 + 2 * (ib + u) + half;
      v[u] = *reinterpret_cast<const float4*>(X + ((size_t)s * BATCH + b) * DIM + d0);
    }
#pragma unroll
    for (int u = 0; u < 8; ++u) {
      const int s = s0 + 2 * (ib + u) + half;
      uint2 p;
      p.x = (unsigned int)f2bf(v[u].x) | ((unsigned int)f2bf(v[u].y) << 16);
      p.y = (unsigned int)f2bf(v[u].z) | ((unsigned int)f2bf(v[u].w) << 16);
      *reinterpret_cast<uint2*>(Xb + ((size_t)b * SLEN + s) * DIM + d0) = p;
      xs.x += v[u].x; xs.y += v[u].y; xs.z += v[u].z; xs.w += v[u].w;
    }
  }
  *reinterpret_cast<float4*>(xsump + ((size_t)b * 8 + sc * 2 + half) * DIM + d0) = xs;
}

// ============ deep-pipelined 256x256 GEMM core (BK=32, 4 LDS buffers) ============
// LDS per buffer: A 256x32 (8192 shorts) + B 256x32 (8192) = 16384 shorts; x4 = 128 KiB.
// Swizzle: 16B granule gI at row r holds global granule gI ^ ((r>>1)&3) (involution,
// applied on pre-swizzled global source AND on ds_read -> conflict-free b128 reads).
// Pipeline: stage(t+3) issued at iter t; s_waitcnt vmcnt(8) (= 2 tiles outstanding)
// + raw s_barrier before reading tile t. Loads span 3 tiles of MFMA (~1000 cy).

#define GEMM_PIPE_LOOP(EXTRA_NONE)                                              \
  f32x4 acc[8][4] = {};                                                         \
  STG(0); STG(1); STG(2);                                                       \
  for (int t = 0; t < 16; ++t) {                                                \
    if (t <= 13) { asm volatile("s_waitcnt vmcnt(8)" ::: "memory"); }           \
    else if (t == 14) { asm volatile("s_waitcnt vmcnt(4)" ::: "memory"); }      \
    else { asm volatile("s_waitcnt vmcnt(0)" ::: "memory"); }                   \
    __builtin_amdgcn_s_barrier();                                               \
    __builtin_amdgcn_sched_barrier(0);                                          \
    if (t + 3 < 16) { STG(t + 3); }                                             \
    __builtin_amdgcn_sched_barrier(0);                                          \
    const unsigned short* la = lds + (t & 3) * 16384;                           \
    const unsigned short* lb2 = la + 8192;                                      \
    v8bf a[8], bbf[4];                                                          \
    _Pragma("unroll")                                                           \
    for (int m = 0; m < 8; ++m)                                                 \
      a[m] = ld8(la + (wr * 128 + m * 16 + c) * 32 + grd);                      \
    _Pragma("unroll")                                                           \
    for (int n = 0; n < 4; ++n)                                                 \
      bbf[n] = ld8(lb2 + (wc * 64 + n * 16 + c) * 32 + grd);                    \
    __builtin_amdgcn_s_setprio(1);                                              \
    _Pragma("unroll")                                                           \
    for (int m = 0; m < 8; ++m)                                                 \
      _Pragma("unroll")                                                         \
      for (int n = 0; n < 4; ++n) acc[m][n] = MFMA(a[m], bbf[n], acc[m][n]);    \
    __builtin_amdgcn_s_setprio(0);                                              \
  }

#define STG(tt) {                                                               \
    const int kc_ = (tt) * 32;                                                  \
    unsigned short* lb_ = lw + ((tt) & 3) * 16384;                              \
    gload16(sAp + kc_, lb_);                                                    \
    gload16(sAp + kc_ + 128 * DIM, lb_ + 4096);                                 \
    gload16(sBp + kc_, lb_ + 8192);                                             \
    gload16(sBp + kc_ + 128 * DIM, lb_ + 12288); }

// ---------- gemm1: u = Xb @ Mt^T (256² tiles); rdpart[j] += sum_e (u+wkr)*x ----------
__global__ __launch_bounds__(512, 2) void gemm1_dp(const unsigned short* __restrict__ Xb,
                                                   const unsigned short* __restrict__ Mt,
                                                   const float* __restrict__ wkr,
                                                   float* __restrict__ rdpart) {
  __shared__ unsigned short lds[65536];  // 128 KiB
  const int tid = threadIdx.x;
  const int lane = tid & 63, w = tid >> 6;
  const int wr = w >> 2, wc = w & 3;
  const int c = lane & 15, g = lane >> 4;
  const int grd = ((g ^ ((c >> 1) & 3))) * 8;

  const int work = (blockIdx.x & 7) * 64 + (blockIdx.x >> 3);  // 512 blocks, 8 XCDs
  const int rt = work >> 1, ct = work & 1;
  const int j0 = rt * 256, e0 = ct * 256;

  // staging decode: thread slot -> (row, swizzled source granule)
  const int rA = tid >> 2;
  const int gl = (tid & 3) ^ ((rA >> 1) & 3);
  const unsigned short* sAp = Xb + (size_t)(j0 + rA) * DIM + gl * 8;
  const unsigned short* sBp = Mt + (size_t)(e0 + rA) * DIM + gl * 8;
  unsigned short* lw = lds + (w << 9);  // wave slot base (+q*4096, +buf*16384)

  GEMM_PIPE_LOOP(0)

  // epilogue: rdpart[j] += sum over this block's e-slice of (u + wkr) * x
  float wkrl[4];
#pragma unroll
  for (int n = 0; n < 4; ++n) wkrl[n] = wkr[e0 + wc * 64 + n * 16 + c];
#pragma unroll
  for (int m = 0; m < 8; ++m) {
#pragma unroll
    for (int i = 0; i < 4; ++i) {
      const int r = wr * 128 + m * 16 + 4 * g + i;
      const unsigned short* xrow = Xb + (size_t)(j0 + r) * DIM + e0 + wc * 64 + c;
      float val = 0.f;
#pragma unroll
      for (int n = 0; n < 4; ++n)
        val += (acc[m][n][i] + wkrl[n]) * bf2f(xrow[n * 16]);
      val += __shfl_xor(val, 1); val += __shfl_xor(val, 2);
      val += __shfl_xor(val, 4); val += __shfl_xor(val, 8);
      if (c == 0) atomicAdd(&rdpart[(size_t)j0 + r], val);
    }
  }
}

// ---------- gemm2: V = Xb @ Wvb^T (256² tiles); out = al*V + be*vs + gam*vw ----------
__global__ __launch_bounds__(512, 2) void gemm2_dp(const unsigned short* __restrict__ Xb,
                                                   const unsigned short* __restrict__ Wvb,
                                                   const float* __restrict__ rd,
                                                   const float* __restrict__ Rsum,
                                                   const float* __restrict__ c2,
                                                   float* __restrict__ out) {
  __shared__ unsigned short lds[65536];
  const int tid = threadIdx.x;
  const int lane = tid & 63, w = tid >> 6;
  const int wr = w >> 2, wc = w & 3;
  const int c = lane & 15, g = lane >> 4;
  const int grd = ((g ^ ((c >> 1) & 3))) * 8;

  const int work = (blockIdx.x & 7) * 64 + (blockIdx.x >> 3);
  const int rt = work >> 1, ct = work & 1;
  const int j0 = rt * 256, e0 = ct * 256;
  const int b = rt;  // 256-row tile == one batch

  const int rA = tid >> 2;
  const int gl = (tid & 3) ^ ((rA >> 1) & 3);
  const unsigned short* sAp = Xb + (size_t)(j0 + rA) * DIM + gl * 8;
  const unsigned short* sBp = Wvb + (size_t)(e0 + rA) * DIM + gl * 8;
  unsigned short* lw = lds + (w << 9);

  GEMM_PIPE_LOOP(0)

  const float invR = 1.0f / Rsum[b];
  const float gam = invR * 0.00390625f;
  float vssl[4], vwsl[4];
#pragma unroll
  for (int n = 0; n < 4; ++n) {
    const int cl = e0 + wc * 64 + n * 16 + c;
    vssl[n] = c2[(size_t)b * DIM + cl];
    vwsl[n] = c2[(size_t)(BATCH + b) * DIM + cl];
  }
#pragma unroll
  for (int m = 0; m < 8; ++m) {
#pragma unroll
    for (int i = 0; i < 4; ++i) {
      const int r = wr * 128 + m * 16 + 4 * g + i;
      const float tt = rd[(size_t)b * SLEN + r] * invR;
      const float al = tt - 0.00390625f;
      const float be = (1.0f - tt) * 0.00390625f;
      float* orow = out + (size_t)(j0 + r) * DIM + e0 + wc * 64 + c;
#pragma unroll
      for (int n = 0; n < 4; ++n)
        orow[n * 16] = al * acc[m][n][i] + be * vssl[n] + gam * vwsl[n];
    }
  }
}

// ---------- fixup1: rd=exp(clip(scale*rdpart)); Rsum; xsum finalize -> u2 rows 0..255 ----------
__global__ __launch_bounds__(256) void fixup1(const float* __restrict__ rdpart,
                                              const float* __restrict__ xsump,
                                              float* __restrict__ rd, float* __restrict__ Rsum,
                                              float* __restrict__ u2) {
  __shared__ float wsum[4];
  const int b = blockIdx.x, tid = threadIdx.x;
  float v = rdpart[(size_t)b * SLEN + tid] * SCALE;
  v = fminf(fmaxf(v, -5.0f), 7.0f);
  const float r = expf(v);
  rd[(size_t)b * SLEN + tid] = r;
  float t = r;
  t += __shfl_xor(t, 1);  t += __shfl_xor(t, 2);  t += __shfl_xor(t, 4);
  t += __shfl_xor(t, 8);  t += __shfl_xor(t, 16); t += __shfl_xor(t, 32);
  if ((tid & 63) == 0) wsum[tid >> 6] = t;
  __syncthreads();
  if (tid == 0) Rsum[b] = wsum[0] + wsum[1] + wsum[2] + wsum[3];

  const int d0 = 2 * tid;
  float2 xs = {0.f, 0.f};
#pragma unroll
  for (int ch = 0; ch < 8; ++ch) {
    const float2 p = *reinterpret_cast<const float2*>(xsump + ((size_t)b * 8 + ch) * DIM + d0);
    xs.x += p.x; xs.y += p.y;
  }
  *reinterpret_cast<float2*>(u2 + (size_t)b * DIM + d0) = xs;
}

// ---------- xwk: u2 row (256+b) += sum_s rd[b,s]*Xb[b,s,:] ----------
__global__ __launch_bounds__(256) void xwk(const unsigned short* __restrict__ Xb,
                                           const float* __restrict__ rd,
                                           float* __restrict__ u2) {
  __shared__ float rds[64];
  const int b = blockIdx.x & 255;
  const int sc = blockIdx.x >> 8;
  const int s0 = sc * 64;
  const int tid = threadIdx.x;
  if (tid < 64) rds[tid] = rd[(size_t)b * SLEN + s0 + tid];
  __syncthreads();
  const int d0 = 2 * tid;
  float a0 = 0.f, a1 = 0.f;
  for (int rb = 0; rb < 64; rb += 8) {
    unsigned int p[8];
#pragma unroll
    for (int u = 0; u < 8; ++u)
      p[u] = *reinterpret_cast<const unsigned int*>(
          Xb + ((size_t)b * SLEN + s0 + rb + u) * DIM + d0);
#pragma unroll
    for (int u = 0; u < 8; ++u) {
      const float rr = rds[rb + u];
      a0 += rr * bf2f((unsigned short)(p[u] & 0xffffu));
      a1 += rr * bf2f((unsigned short)(p[u] >> 16));
    }
  }
  atomicAdd(&u2[(size_t)(BATCH + b) * DIM + d0], a0);
  atomicAdd(&u2[(size_t)(BATCH + b) * DIM + d0 + 1], a1);
}

// ---------- vsvw: c2 = u2 @ Wv^T (f32, 512x512x512) ----------
__global__ __launch_bounds__(256) void vsvw(const float* __restrict__ u2,
                                            const float* __restrict__ Wv,
                                            float* __restrict__ c2) {
  __shared__ float Us[32][33];
  __shared__ float Ws[32][33];
  const int r0 = (blockIdx.x & 15) * 32;
  const int e0 = (blockIdx.x >> 4) * 32;
  const int tid = threadIdx.x;
  const int tm = (tid & 15) * 2;
  const int tn = (tid >> 4) * 2;
  const int lf = tid >> 3;
  const int lc = (tid & 7) * 4;
  float a00 = 0.f, a01 = 0.f, a10 = 0.f, a11 = 0.f;
  for (int k0 = 0; k0 < DIM; k0 += 32) {
    __syncthreads();
    const float4 a = *reinterpret_cast<const float4*>(u2 + (size_t)(r0 + lf) * DIM + k0 + lc);
    const float4 w = *reinterpret_cast<const float4*>(Wv + (size_t)(e0 + lf) * DIM + k0 + lc);
    Us[lf][lc] = a.x; Us[lf][lc + 1] = a.y; Us[lf][lc + 2] = a.z; Us[lf][lc + 3] = a.w;
    Ws[lf][lc] = w.x; Ws[lf][lc + 1] = w.y; Ws[lf][lc + 2] = w.z; Ws[lf][lc + 3] = w.w;
    __syncthreads();
#pragma unroll
    for (int k = 0; k < 32; ++k) {
      const float x0 = Us[tm][k], x1 = Us[tm + 1][k];
      const float y0 = Ws[tn][k], y1 = Ws[tn + 1][k];
      a00 += x0 * y0; a01 += x0 * y1; a10 += x1 * y0; a11 += x1 * y1;
    }
  }
  c2[(size_t)(r0 + tm) * DIM + e0 + tn] = a00;
  c2[(size_t)(r0 + tm) * DIM + e0 + tn + 1] = a01;
  c2[(size_t)(r0 + tm + 1) * DIM + e0 + tn] = a10;
  c2[(size_t)(r0 + tm + 1) * DIM + e0 + tn + 1] = a11;
}

// =================== round-1 fallback kernels (verified) ===================
__global__ __launch_bounds__(256, 2) void pass1_fb(
    const float* __restrict__ X, const unsigned short* __restrict__ Mt,
    const float* __restrict__ wkr, float* __restrict__ rd_out,
    float* __restrict__ Rsum, float* __restrict__ xsum, float* __restrict__ xw) {
  __shared__ __align__(16) unsigned short Xs[TS * LDX];
  __shared__ __align__(16) unsigned short Bsh[64 * LDB];
  __shared__ float wkrs[DIM];
  __shared__ float dacc[TS];
  __shared__ float rds[TS];
  const int tid = threadIdx.x;
  const int b = blockIdx.x & 255;
  const int s0 = (blockIdx.x >> 8) * TS;
  const int lane = tid & 63;
  const int wave = tid >> 6;
  const int wr = wave >> 1, wc = wave & 1;
  const int g = lane >> 4, c = lane & 15;
#pragma unroll 4
  for (int r = 0; r < TS; ++r) {
    const float2 v = *reinterpret_cast<const float2*>(
        X + ((size_t)(s0 + r) * BATCH + b) * DIM + tid * 2);
    Xs[r * LDX + tid * 2] = f2bf(v.x);
    Xs[r * LDX + tid * 2 + 1] = f2bf(v.y);
  }
  wkrs[tid] = wkr[tid];
  wkrs[tid + 256] = wkr[tid + 256];
  if (tid < TS) dacc[tid] = 0.f;
  float dp0[4] = {0.f, 0.f, 0.f, 0.f};
  float dp1[4] = {0.f, 0.f, 0.f, 0.f};
  for (int et = 0; et < 8; ++et) {
    const int e0 = et * 64;
    f32x4 acc00 = {0.f,0.f,0.f,0.f}, acc01 = {0.f,0.f,0.f,0.f};
    f32x4 acc10 = {0.f,0.f,0.f,0.f}, acc11 = {0.f,0.f,0.f,0.f};
    for (int kc0 = 0; kc0 < DIM; kc0 += KC) {
      __syncthreads();
      {
        const int e = tid >> 2;
        const int kq = (tid & 3) * 16;
        const uint4* src = reinterpret_cast<const uint4*>(Mt + (size_t)(e0 + e) * DIM + kc0 + kq);
        const uint4 w0 = src[0];
        const uint4 w1 = src[1];
        *reinterpret_cast<uint4*>(&Bsh[e * LDB + kq]) = w0;
        *reinterpret_cast<uint4*>(&Bsh[e * LDB + kq + 8]) = w1;
      }
      __syncthreads();
#pragma unroll
      for (int ks = 0; ks < KC; ks += 32) {
        const int ka = kc0 + ks + 8 * g;
        const int kb = ks + 8 * g;
        const v8bf fa0 = ld8(&Xs[(32 * wr + c) * LDX + ka]);
        const v8bf fa1 = ld8(&Xs[(32 * wr + 16 + c) * LDX + ka]);
        const v8bf fb0 = ld8(&Bsh[(32 * wc + c) * LDB + kb]);
        const v8bf fb1 = ld8(&Bsh[(32 * wc + 16 + c) * LDB + kb]);
        acc00 = MFMA(fa0, fb0, acc00);
        acc01 = MFMA(fa0, fb1, acc01);
        acc10 = MFMA(fa1, fb0, acc10);
        acc11 = MFMA(fa1, fb1, acc11);
      }
    }
#pragma unroll
    for (int i = 0; i < 4; ++i) {
      const int r0 = 32 * wr + 4 * g + i;
      const int ec0 = e0 + 32 * wc + c;
      const float w0 = wkrs[ec0], w1 = wkrs[ec0 + 16];
      dp0[i] += (acc00[i] + w0) * bf2f(Xs[r0 * LDX + ec0]) +
                (acc01[i] + w1) * bf2f(Xs[r0 * LDX + ec0 + 16]);
      dp1[i] += (acc10[i] + w0) * bf2f(Xs[(r0 + 16) * LDX + ec0]) +
                (acc11[i] + w1) * bf2f(Xs[(r0 + 16) * LDX + ec0 + 16]);
    }
  }
#pragma unroll
  for (int i = 0; i < 4; ++i) {
    float v0 = dp0[i], v1 = dp1[i];
    v0 += __shfl_xor(v0, 1); v0 += __shfl_xor(v0, 2);
    v0 += __shfl_xor(v0, 4); v0 += __shfl_xor(v0, 8);
    v1 += __shfl_xor(v1, 1); v1 += __shfl_xor(v1, 2);
    v1 += __shfl_xor(v1, 4); v1 += __shfl_xor(v1, 8);
    if (c == 0) {
      atomicAdd(&dacc[32 * wr + 4 * g + i], v0);
      atomicAdd(&dacc[32 * wr + 16 + 4 * g + i], v1);
    }
  }
  __syncthreads();
  if (tid < TS) {
    float sc = dacc[tid] * SCALE;
    sc = fminf(fmaxf(sc, -5.0f), 7.0f);
    const float r = expf(sc);
    rds[tid] = r;
    rd_out[(size_t)b * SLEN + s0 + tid] = r;
    float t = r;
    t += __shfl_xor(t, 1); t += __shfl_xor(t, 2); t += __shfl_xor(t, 4);
    t += __shfl_xor(t, 8); t += __shfl_xor(t, 16); t += __shfl_xor(t, 32);
    if (tid == 0) atomicAdd(&Rsum[b], t);
  }
  __syncthreads();
#pragma unroll
  for (int dd = 0; dd < 2; ++dd) {
    const int d = tid + dd * 256;
    float s1 = 0.f, s2 = 0.f;
    for (int r = 0; r < TS; ++r) {
      const float xv = bf2f(Xs[r * LDX + d]);
      s1 += xv;
      s2 += rds[r] * xv;
    }
    atomicAdd(&xsum[(size_t)b * DIM + d], s1);
    atomicAdd(&xw[(size_t)b * DIM + d], s2);
  }
}

__global__ __launch_bounds__(256, 2) void pass2_fb(
    const float* __restrict__ X, const unsigned short* __restrict__ Wvb,
    const float* __restrict__ rd, const float* __restrict__ Rsum,
    const float* __restrict__ xsum, const float* __restrict__ xw,
    float* __restrict__ out) {
  __shared__ __align__(16) unsigned short Zs[TS * LDX];
  __shared__ __align__(16) unsigned short Bsh[64 * LDB];
  __shared__ float xss[DIM];
  __shared__ float xws[DIM];
  __shared__ float rds[TS];
  const int tid = threadIdx.x;
  const int b = blockIdx.x & 255;
  const int s0 = (blockIdx.x >> 8) * TS;
  const int lane = tid & 63;
  const int wave = tid >> 6;
  const int wr = wave >> 1, wc = wave & 1;
  const int g = lane >> 4, c = lane & 15;
  xss[tid] = xsum[(size_t)b * DIM + tid];
  xss[tid + 256] = xsum[(size_t)b * DIM + tid + 256];
  xws[tid] = xw[(size_t)b * DIM + tid];
  xws[tid + 256] = xw[(size_t)b * DIM + tid + 256];
  if (tid < TS) rds[tid] = rd[(size_t)b * SLEN + s0 + tid];
  const float Rb = Rsum[b];
  const float invR = 1.0f / Rb;
  const float gam = invR * (1.0f / 256.0f);
  __syncthreads();
#pragma unroll 4
  for (int r = 0; r < TS; ++r) {
    const float rv = rds[r];
    const float al = rv * invR - (1.0f / 256.0f);
    const float be = (1.0f - rv * invR) * (1.0f / 256.0f);
    const float2 v = *reinterpret_cast<const float2*>(
        X + ((size_t)(s0 + r) * BATCH + b) * DIM + tid * 2);
    const int d0 = tid * 2;
    Zs[r * LDX + d0] = f2bf(al * v.x + be * xss[d0] + gam * xws[d0]);
    Zs[r * LDX + d0 + 1] = f2bf(al * v.y + be * xss[d0 + 1] + gam * xws[d0 + 1]);
  }
  const size_t outbase = ((size_t)b * SLEN + s0) * DIM;
  for (int et = 0; et < 8; ++et) {
    const int e0 = et * 64;
    f32x4 acc00 = {0.f,0.f,0.f,0.f}, acc01 = {0.f,0.f,0.f,0.f};
    f32x4 acc10 = {0.f,0.f,0.f,0.f}, acc11 = {0.f,0.f,0.f,0.f};
    for (int kc0 = 0; kc0 < DIM; kc0 += KC) {
      __syncthreads();
      {
        const int e = tid >> 2;
        const int kq = (tid & 3) * 16;
        const uint4* src = reinterpret_cast<const uint4*>(Wvb + (size_t)(e0 + e) * DIM + kc0 + kq);
        const uint4 w0 = src[0];
        const uint4 w1 = src[1];
        *reinterpret_cast<uint4*>(&Bsh[e * LDB + kq]) = w0;
        *reinterpret_cast<uint4*>(&Bsh[e * LDB + kq + 8]) = w1;
      }
      __syncthreads();
#pragma unroll
      for (int ks = 0; ks < KC; ks += 32) {
        const int ka = kc0 + ks + 8 * g;
        const int kb = ks + 8 * g;
        const v8bf fa0 = ld8(&Zs[(32 * wr + c) * LDX + ka]);
        const v8bf fa1 = ld8(&Zs[(32 * wr + 16 + c) * LDX + ka]);
        const v8bf fb0 = ld8(&Bsh[(32 * wc + c) * LDB + kb]);
        const v8bf fb1 = ld8(&Bsh[(32 * wc + 16 + c) * LDB + kb]);
        acc00 = MFMA(fa0, fb0, acc00);
        acc01 = MFMA(fa0, fb1, acc01);
        acc10 = MFMA(fa1, fb0, acc10);
        acc11 = MFMA(fa1, fb1, acc11);
      }
    }
#pragma unroll
    for (int i = 0; i < 4; ++i) {
      const int r0 = 32 * wr + 4 * g + i;
      const int c0 = e0 + 32 * wc + c;
      out[outbase + (size_t)r0 * DIM + c0] = acc00[i];
      out[outbase + (size_t)r0 * DIM + c0 + 16] = acc01[i];
      out[outbase + (size_t)(r0 + 16) * DIM + c0] = acc10[i];
      out[outbase + (size_t)(r0 + 16) * DIM + c0 + 16] = acc11[i];
    }
  }
}

extern "C" void kernel_launch(void* const* d_in, const int* in_sizes, int n_in,
                              void* d_out, int out_size, void* d_ws, size_t ws_size,
                              hipStream_t stream) {
  (void)in_sizes; (void)n_in; (void)out_size;
  const float* X = (const float*)d_in[0];
  const float* Wq = (const float*)d_in[1];
  const float* Wk = (const float*)d_in[2];
  const float* Wv = (const float*)d_in[3];
  const float* rq = (const float*)d_in[4];
  float* out = (float*)d_out;
  char* ws = (char*)d_ws;

  unsigned short* Mt = (unsigned short*)(ws + 0);        // 512 KB
  unsigned short* Wvb = (unsigned short*)(ws + 524288);  // 512 KB

  const size_t NEED = 74981376;  // fast path workspace footprint
  if (ws_size >= NEED) {
    float* wkr = (float*)(ws + 1048576);            // 2 KB   (zeroed)
    float* rdpart = (float*)(ws + 1052672);         // 256 KB (zeroed)
    float* u2 = (float*)(ws + 1314816);             // 1 MB   (zeroed)
    float* c2 = (float*)(ws + 2363392);             // 1 MB
    float* rd = (float*)(ws + 3411968);             // 256 KB
    float* Rsum = (float*)(ws + 3674112);           // 4 KB
    float* xsump = (float*)(ws + 3678208);          // 4 MB
    unsigned short* Xb = (unsigned short*)(ws + 7872512);  // 64 MB

    // zero wkr..u2 (1314816 B = 82176 float4)
    zf<<<dim3(321), dim3(256), 0, stream>>>((float4*)(ws + 1048576), 82176);

    prep_mt<<<dim3(256), dim3(256), 0, stream>>>(Wq, Wk, Mt);
    conv_wv<<<dim3(256), dim3(256), 0, stream>>>(Wv, Wvb);
    wkr_k3<<<dim3(16), dim3(256), 0, stream>>>(Wk, rq, wkr);
    x2b<<<dim3(1024), dim3(256), 0, stream>>>(X, Xb, xsump);
    gemm1_dp<<<dim3(512), dim3(512), 0, stream>>>(Xb, Mt, wkr, rdpart);
    fixup1<<<dim3(256), dim3(256), 0, stream>>>(rdpart, xsump, rd, Rsum, u2);
    xwk<<<dim3(1024), dim3(256), 0, stream>>>(Xb, rd, u2);
    vsvw<<<dim3(256), dim3(256), 0, stream>>>(u2, Wv, c2);
    gemm2_dp<<<dim3(512), dim3(512), 0, stream>>>(Xb, Wvb, rd, Rsum, c2, out);
  } else {
    // round-1 verified fallback (needs ~2.4 MB)
    float* rd = (float*)(ws + 1048576);
    float* wkr = (float*)(ws + 1310720);
    float* Rsum = (float*)(ws + 1312768);
    float* xsum = (float*)(ws + 1313792);
    float* xw = (float*)(ws + 1838080);
    zf<<<dim3(257), dim3(256), 0, stream>>>((float4*)(ws + 1310720), 65728);
    prep_mt<<<dim3(256), dim3(256), 0, stream>>>(Wq, Wk, Mt);
    conv_wv<<<dim3(256), dim3(256), 0, stream>>>(Wv, Wvb);
    wkr_k2<<<dim3(2), dim3(256), 0, stream>>>(Wk, rq, wkr);
    pass1_fb<<<dim3(1024), dim3(256), 0, stream>>>(X, Mt, wkr, rd, Rsum, xsum, xw);
    pass2_fb<<<dim3(1024), dim3(256), 0, stream>>>(X, Wvb, rd, Rsum, xsum, xw, out);
  }
}

// Round 6
// 186.995 us; speedup vs baseline: 1.3627x; 1.1946x over previous
//
#include <hip/hip_runtime.h>

typedef __bf16 v8bf __attribute__((ext_vector_type(8)));
typedef float f32x4 __attribute__((ext_vector_type(4)));
typedef unsigned short u16x8 __attribute__((ext_vector_type(8)));

#define SLEN 256
#define BATCH 256
#define DIM 512
#define SCALE 0.044194173824159216f  // sqrt(1/512)

// fallback-path tile params (round-1 verified kernels)
#define TS 64
#define LDX 520
#define LDB 72
#define KC 64

#define MFMA(a, b, c) __builtin_amdgcn_mfma_f32_16x16x32_bf16((a), (b), (c), 0, 0, 0)

__device__ __forceinline__ unsigned short f2bf(float f) {
  union { float f; unsigned int u; } v; v.f = f;
  unsigned int r = v.u + 0x7FFFu + ((v.u >> 16) & 1u);  // RNE
  return (unsigned short)(r >> 16);
}
__device__ __forceinline__ float bf2f(unsigned short u) {
  union { unsigned int u; float f; } v; v.u = ((unsigned int)u) << 16;
  return v.f;
}
__device__ __forceinline__ v8bf ld8(const unsigned short* p) {
  u16x8 t = *reinterpret_cast<const u16x8*>(p);
  return __builtin_bit_cast(v8bf, t);
}
// async global->LDS, 16B per lane; lds base must be wave-uniform
__device__ __forceinline__ void gload16(const unsigned short* g, unsigned short* l) {
  __builtin_amdgcn_global_load_lds(
      (const __attribute__((address_space(1))) unsigned int*)g,
      (__attribute__((address_space(3))) unsigned int*)l, 16, 0, 0);
}

// ---------- zf: fast zero-fill (fallback path only) ----------
__global__ __launch_bounds__(256) void zf(float4* __restrict__ p, int n4) {
  const int i = blockIdx.x * 256 + threadIdx.x;
  if (i < n4) {
    const float4 z = {0.f, 0.f, 0.f, 0.f};
    p[i] = z;
  }
}

// ---------- prep_all: fused x2b (1024 blk) + prep_mt (256) + conv_wv (256) + wkr (2) ----------
__global__ __launch_bounds__(256) void prep_all(const float* __restrict__ X,
                                                const float* __restrict__ Wq,
                                                const float* __restrict__ Wk,
                                                const float* __restrict__ Wv,
                                                const float* __restrict__ rq,
                                                unsigned short* __restrict__ Xb,
                                                unsigned short* __restrict__ Mt,
                                                unsigned short* __restrict__ Wvb,
                                                float* __restrict__ wkr) {
  __shared__ float As[32][33];
  __shared__ float Bs[32][33];
  const int blk = blockIdx.x;
  const int tid = threadIdx.x;

  if (blk < 1024) {
    // ---- x2b role: X[s,b,d] f32 -> Xb[b,s,d] bf16 ----
    const int b = blk & 255;
    const int sc = blk >> 8;
    const int s0 = sc * 64;
    const int half = tid >> 7;
    const int d0 = (tid & 127) * 4;
    for (int ib = 0; ib < 32; ib += 8) {
      float4 v[8];
#pragma unroll
      for (int u = 0; u < 8; ++u) {
        const int s = s0 + 2 * (ib + u) + half;
        v[u] = *reinterpret_cast<const float4*>(X + ((size_t)s * BATCH + b) * DIM + d0);
      }
#pragma unroll
      for (int u = 0; u < 8; ++u) {
        const int s = s0 + 2 * (ib + u) + half;
        uint2 p;
        p.x = (unsigned int)f2bf(v[u].x) | ((unsigned int)f2bf(v[u].y) << 16);
        p.y = (unsigned int)f2bf(v[u].z) | ((unsigned int)f2bf(v[u].w) << 16);
        *reinterpret_cast<uint2*>(Xb + ((size_t)b * SLEN + s) * DIM + d0) = p;
      }
    }
  } else if (blk < 1280) {
    // ---- prep_mt role: Mt[e][d] = sum_f Wk[f,e]*Wq[f,d] ----
    const int bid = blk - 1024;
    const int e0 = (bid & 15) * 32;
    const int d0 = (bid >> 4) * 32;
    const int tm = (tid & 15) * 2;
    const int tn = (tid >> 4) * 2;
    const int lf = tid >> 3;
    const int lc = (tid & 7) * 4;
    float a00 = 0.f, a01 = 0.f, a10 = 0.f, a11 = 0.f;
    for (int f0 = 0; f0 < DIM; f0 += 32) {
      __syncthreads();
      const float4 a = *reinterpret_cast<const float4*>(Wk + (size_t)(f0 + lf) * DIM + e0 + lc);
      const float4 b = *reinterpret_cast<const float4*>(Wq + (size_t)(f0 + lf) * DIM + d0 + lc);
      As[lf][lc] = a.x; As[lf][lc + 1] = a.y; As[lf][lc + 2] = a.z; As[lf][lc + 3] = a.w;
      Bs[lf][lc] = b.x; Bs[lf][lc + 1] = b.y; Bs[lf][lc + 2] = b.z; Bs[lf][lc + 3] = b.w;
      __syncthreads();
#pragma unroll
      for (int k = 0; k < 32; ++k) {
        const float x0 = As[k][tm], x1 = As[k][tm + 1];
        const float y0 = Bs[k][tn], y1 = Bs[k][tn + 1];
        a00 += x0 * y0; a01 += x0 * y1; a10 += x1 * y0; a11 += x1 * y1;
      }
    }
    Mt[(size_t)(e0 + tm) * DIM + d0 + tn] = f2bf(a00);
    Mt[(size_t)(e0 + tm) * DIM + d0 + tn + 1] = f2bf(a01);
    Mt[(size_t)(e0 + tm + 1) * DIM + d0 + tn] = f2bf(a10);
    Mt[(size_t)(e0 + tm + 1) * DIM + d0 + tn + 1] = f2bf(a11);
  } else if (blk < 1536) {
    // ---- conv_wv role ----
    const int idx = ((blk - 1280) * 256 + tid) * 4;
    const float4 v = *reinterpret_cast<const float4*>(Wv + idx);
    uint2 p;
    p.x = (unsigned int)f2bf(v.x) | ((unsigned int)f2bf(v.y) << 16);
    p.y = (unsigned int)f2bf(v.z) | ((unsigned int)f2bf(v.w) << 16);
    *reinterpret_cast<uint2*>(Wvb + idx) = p;
  } else {
    // ---- wkr role (2 blocks): wkr[d] = sum_f Wk[f,d]*rq[f], plain store ----
    float* rqs = &As[0][0];  // 512 floats fits in As
    rqs[tid] = rq[tid];
    rqs[tid + 256] = rq[tid + 256];
    __syncthreads();
    const int d = (blk - 1536) * 256 + tid;
    float s = 0.f;
#pragma unroll 8
    for (int f = 0; f < DIM; ++f) s += Wk[(size_t)f * DIM + d] * rqs[f];
    wkr[d] = s;
  }
}

// ============ deep-pipelined 256x256 GEMM core (BK=32, 4 LDS buffers) ============
// Verified in round 5. Swizzle: 16B granule gI at row r holds global granule
// gI ^ ((r>>1)&3); applied on pre-swizzled global source AND on ds_read.
// Counted vmcnt(8) = 2 tiles outstanding; prefetch distance 3 tiles.

#define GEMM_PROLOGUE()                                                         \
  f32x4 acc[8][4] = {};                                                         \
  STG(0); STG(1); STG(2);

#define GEMM_MAIN_LOOP()                                                        \
  for (int t = 0; t < 16; ++t) {                                                \
    if (t <= 13) { asm volatile("s_waitcnt vmcnt(8)" ::: "memory"); }           \
    else if (t == 14) { asm volatile("s_waitcnt vmcnt(4)" ::: "memory"); }      \
    else { asm volatile("s_waitcnt vmcnt(0)" ::: "memory"); }                   \
    __builtin_amdgcn_s_barrier();                                               \
    __builtin_amdgcn_sched_barrier(0);                                          \
    if (t + 3 < 16) { STG(t + 3); }                                             \
    __builtin_amdgcn_sched_barrier(0);                                          \
    const unsigned short* la = lds + (t & 3) * 16384;                           \
    const unsigned short* lb2 = la + 8192;                                      \
    v8bf a[8], bbf[4];                                                          \
    _Pragma("unroll")                                                           \
    for (int m = 0; m < 8; ++m)                                                 \
      a[m] = ld8(la + (wr * 128 + m * 16 + c) * 32 + grd);                      \
    _Pragma("unroll")                                                           \
    for (int n = 0; n < 4; ++n)                                                 \
      bbf[n] = ld8(lb2 + (wc * 64 + n * 16 + c) * 32 + grd);                    \
    __builtin_amdgcn_s_setprio(1);                                              \
    _Pragma("unroll")                                                           \
    for (int m = 0; m < 8; ++m)                                                 \
      _Pragma("unroll")                                                         \
      for (int n = 0; n < 4; ++n) acc[m][n] = MFMA(a[m], bbf[n], acc[m][n]);    \
    __builtin_amdgcn_s_setprio(0);                                              \
  }

#define STG(tt) {                                                               \
    const int kc_ = (tt) * 32;                                                  \
    unsigned short* lb_ = lw + ((tt) & 3) * 16384;                              \
    gload16(sAp + kc_, lb_);                                                    \
    gload16(sAp + kc_ + 128 * DIM, lb_ + 4096);                                 \
    gload16(sBp + kc_, lb_ + 8192);                                             \
    gload16(sBp + kc_ + 128 * DIM, lb_ + 12288); }

// ---------- gemm1: u = Xb @ Mt^T; rdpart[ct][j] = sum_e-slice (u+wkr)*x (no atomics) ----------
__global__ __launch_bounds__(512, 2) void gemm1_dp(const unsigned short* __restrict__ Xb,
                                                   const unsigned short* __restrict__ Mt,
                                                   const float* __restrict__ wkr,
                                                   float* __restrict__ rdpart) {
  __shared__ unsigned short lds[65536];  // 128 KiB
  const int tid = threadIdx.x;
  const int lane = tid & 63, w = tid >> 6;
  const int wr = w >> 2, wc = w & 3;
  const int c = lane & 15, g = lane >> 4;
  const int grd = ((g ^ ((c >> 1) & 3))) * 8;

  const int work = (blockIdx.x & 7) * 64 + (blockIdx.x >> 3);  // 512 blocks, 8 XCDs
  const int rt = work >> 1, ct = work & 1;
  const int j0 = rt * 256, e0 = ct * 256;

  const int rA = tid >> 2;
  const int gl = (tid & 3) ^ ((rA >> 1) & 3);
  const unsigned short* sAp = Xb + (size_t)(j0 + rA) * DIM + gl * 8;
  const unsigned short* sBp = Mt + (size_t)(e0 + rA) * DIM + gl * 8;
  unsigned short* lw = lds + (w << 9);

  GEMM_PROLOGUE()
  GEMM_MAIN_LOOP()

  // epilogue: per-row dot with x over this block's e-slice, LDS cross-wave combine
  __syncthreads();
  float* red = (float*)lds;  // 4 wc-slices x 256 rows
  float wkrl[4];
#pragma unroll
  for (int n = 0; n < 4; ++n) wkrl[n] = wkr[e0 + wc * 64 + n * 16 + c];
#pragma unroll
  for (int m = 0; m < 8; ++m) {
#pragma unroll
    for (int i = 0; i < 4; ++i) {
      const int rl = wr * 128 + m * 16 + 4 * g + i;
      const unsigned short* xrow = Xb + (size_t)(j0 + rl) * DIM + e0 + wc * 64 + c;
      float val = 0.f;
#pragma unroll
      for (int n = 0; n < 4; ++n)
        val += (acc[m][n][i] + wkrl[n]) * bf2f(xrow[n * 16]);
      val += __shfl_xor(val, 1); val += __shfl_xor(val, 2);
      val += __shfl_xor(val, 4); val += __shfl_xor(val, 8);
      if (c == 0) red[wc * 256 + rl] = val;
    }
  }
  __syncthreads();
  if (tid < 256) {
    const float s = red[tid] + red[256 + tid] + red[512 + tid] + red[768 + tid];
    rdpart[(size_t)ct * 65536 + j0 + tid] = s;
  }
}

// ---------- gemm2: rd/Rsum from rdpart; V = Xb @ Wvb^T; vs/vw reduced in-block;
//            out = (rd_j/R - 1/s)*V + ((1-rd_j/R)/s)*vs + (1/(sR))*vw ----------
__global__ __launch_bounds__(512, 2) void gemm2_f(const unsigned short* __restrict__ Xb,
                                                  const unsigned short* __restrict__ Wvb,
                                                  const float* __restrict__ rdpart,
                                                  float* __restrict__ out) {
  __shared__ unsigned short lds[65536];
  __shared__ float rdl[256];
  __shared__ float wsum[4];
  const int tid = threadIdx.x;
  const int lane = tid & 63, w = tid >> 6;
  const int wr = w >> 2, wc = w & 3;
  const int c = lane & 15, g = lane >> 4;
  const int grd = ((g ^ ((c >> 1) & 3))) * 8;

  const int work = (blockIdx.x & 7) * 64 + (blockIdx.x >> 3);
  const int rt = work >> 1, ct = work & 1;
  const int j0 = rt * 256, e0 = ct * 256;
  const int b = rt;  // 256-row tile == one batch

  // rd + Rsum (tiny, before any pipeline loads so __syncthreads drains nothing)
  if (tid < 256) {
    float v = (rdpart[(size_t)b * SLEN + tid] + rdpart[65536 + (size_t)b * SLEN + tid]) * SCALE;
    v = fminf(fmaxf(v, -5.0f), 7.0f);
    const float r = expf(v);
    rdl[tid] = r;
    float t = r;
    t += __shfl_xor(t, 1);  t += __shfl_xor(t, 2);  t += __shfl_xor(t, 4);
    t += __shfl_xor(t, 8);  t += __shfl_xor(t, 16); t += __shfl_xor(t, 32);
    if ((tid & 63) == 0) wsum[tid >> 6] = t;
  }
  __syncthreads();

  const int rA = tid >> 2;
  const int gl = (tid & 3) ^ ((rA >> 1) & 3);
  const unsigned short* sAp = Xb + (size_t)(j0 + rA) * DIM + gl * 8;
  const unsigned short* sBp = Wvb + (size_t)(e0 + rA) * DIM + gl * 8;
  unsigned short* lw = lds + (w << 9);

  GEMM_PROLOGUE()
  GEMM_MAIN_LOOP()

  // ---- in-block vs/vw reduction over the 256 rows (= full batch) ----
  float vsp[4] = {0.f, 0.f, 0.f, 0.f}, vwp[4] = {0.f, 0.f, 0.f, 0.f};
#pragma unroll
  for (int m = 0; m < 8; ++m) {
#pragma unroll
    for (int i = 0; i < 4; ++i) {
      const int rl = wr * 128 + m * 16 + 4 * g + i;
      const float rr = rdl[rl];
#pragma unroll
      for (int n = 0; n < 4; ++n) {
        vsp[n] += acc[m][n][i];
        vwp[n] += rr * acc[m][n][i];
      }
    }
  }
#pragma unroll
  for (int n = 0; n < 4; ++n) {
    vsp[n] += __shfl_xor(vsp[n], 16); vsp[n] += __shfl_xor(vsp[n], 32);
    vwp[n] += __shfl_xor(vwp[n], 16); vwp[n] += __shfl_xor(vwp[n], 32);
  }
  __syncthreads();  // pipeline LDS free now
  float* red = (float*)lds;  // [2][8 waves][4 n][16 c]
  if (g == 0) {
#pragma unroll
    for (int n = 0; n < 4; ++n) {
      red[(w * 4 + n) * 16 + c] = vsp[n];
      red[512 + (w * 4 + n) * 16 + c] = vwp[n];
    }
  }
  __syncthreads();
  const float Rb = wsum[0] + wsum[1] + wsum[2] + wsum[3];
  const float invR = 1.0f / Rb;
  const float gam = invR * 0.00390625f;
  const int wo = w ^ 4;  // other wr half, same wc
  float vsf[4], vwf[4];
#pragma unroll
  for (int n = 0; n < 4; ++n) {
    vsf[n] = red[(w * 4 + n) * 16 + c] + red[(wo * 4 + n) * 16 + c];
    vwf[n] = red[512 + (w * 4 + n) * 16 + c] + red[512 + (wo * 4 + n) * 16 + c];
  }
#pragma unroll
  for (int m = 0; m < 8; ++m) {
#pragma unroll
    for (int i = 0; i < 4; ++i) {
      const int rl = wr * 128 + m * 16 + 4 * g + i;
      const float tt = rdl[rl] * invR;
      const float al = tt - 0.00390625f;
      const float be = (1.0f - tt) * 0.00390625f;
      float* orow = out + (size_t)(j0 + rl) * DIM + e0 + wc * 64 + c;
#pragma unroll
      for (int n = 0; n < 4; ++n)
        orow[n * 16] = al * acc[m][n][i] + be * vsf[n] + gam * vwf[n];
    }
  }
}

// =================== fallback prep kernels (round-1 verified) ===================
__global__ __launch_bounds__(256) void prep_mt(const float* __restrict__ Wq,
                                               const float* __restrict__ Wk,
                                               unsigned short* __restrict__ Mt) {
  __shared__ float As[32][33];
  __shared__ float Bs[32][33];
  const int e0 = (blockIdx.x & 15) * 32;
  const int d0 = (blockIdx.x >> 4) * 32;
  const int tid = threadIdx.x;
  const int tm = (tid & 15) * 2;
  const int tn = (tid >> 4) * 2;
  const int lf = tid >> 3;
  const int lc = (tid & 7) * 4;
  float a00 = 0.f, a01 = 0.f, a10 = 0.f, a11 = 0.f;
  for (int f0 = 0; f0 < DIM; f0 += 32) {
    __syncthreads();
    const float4 a = *reinterpret_cast<const float4*>(Wk + (size_t)(f0 + lf) * DIM + e0 + lc);
    const float4 b = *reinterpret_cast<const float4*>(Wq + (size_t)(f0 + lf) * DIM + d0 + lc);
    As[lf][lc] = a.x; As[lf][lc + 1] = a.y; As[lf][lc + 2] = a.z; As[lf][lc + 3] = a.w;
    Bs[lf][lc] = b.x; Bs[lf][lc + 1] = b.y; Bs[lf][lc + 2] = b.z; Bs[lf][lc + 3] = b.w;
    __syncthreads();
#pragma unroll
    for (int k = 0; k < 32; ++k) {
      const float x0 = As[k][tm], x1 = As[k][tm + 1];
      const float y0 = Bs[k][tn], y1 = Bs[k][tn + 1];
      a00 += x0 * y0; a01 += x0 * y1; a10 += x1 * y0; a11 += x1 * y1;
    }
  }
  Mt[(size_t)(e0 + tm) * DIM + d0 + tn] = f2bf(a00);
  Mt[(size_t)(e0 + tm) * DIM + d0 + tn + 1] = f2bf(a01);
  Mt[(size_t)(e0 + tm + 1) * DIM + d0 + tn] = f2bf(a10);
  Mt[(size_t)(e0 + tm + 1) * DIM + d0 + tn + 1] = f2bf(a11);
}

__global__ __launch_bounds__(256) void conv_wv(const float* __restrict__ Wv,
                                               unsigned short* __restrict__ Wvb) {
  const int idx = (blockIdx.x * 256 + threadIdx.x) * 4;
  const float4 v = *reinterpret_cast<const float4*>(Wv + idx);
  uint2 p;
  p.x = (unsigned int)f2bf(v.x) | ((unsigned int)f2bf(v.y) << 16);
  p.y = (unsigned int)f2bf(v.z) | ((unsigned int)f2bf(v.w) << 16);
  *reinterpret_cast<uint2*>(Wvb + idx) = p;
}

__global__ __launch_bounds__(256) void wkr_k2(const float* __restrict__ Wk,
                                              const float* __restrict__ rq,
                                              float* __restrict__ wkr) {
  __shared__ float rqs[DIM];
  const int tid = threadIdx.x;
  rqs[tid] = rq[tid];
  rqs[tid + 256] = rq[tid + 256];
  __syncthreads();
  const int d = blockIdx.x * 256 + tid;
  float s = 0.f;
#pragma unroll 8
  for (int f = 0; f < DIM; ++f) s += Wk[(size_t)f * DIM + d] * rqs[f];
  wkr[d] = s;
}

// =================== round-1 fallback main kernels (verified) ===================
__global__ __launch_bounds__(256, 2) void pass1_fb(
    const float* __restrict__ X, const unsigned short* __restrict__ Mt,
    const float* __restrict__ wkr, float* __restrict__ rd_out,
    float* __restrict__ Rsum, float* __restrict__ xsum, float* __restrict__ xw) {
  __shared__ __align__(16) unsigned short Xs[TS * LDX];
  __shared__ __align__(16) unsigned short Bsh[64 * LDB];
  __shared__ float wkrs[DIM];
  __shared__ float dacc[TS];
  __shared__ float rds[TS];
  const int tid = threadIdx.x;
  const int b = blockIdx.x & 255;
  const int s0 = (blockIdx.x >> 8) * TS;
  const int lane = tid & 63;
  const int wave = tid >> 6;
  const int wr = wave >> 1, wc = wave & 1;
  const int g = lane >> 4, c = lane & 15;
#pragma unroll 4
  for (int r = 0; r < TS; ++r) {
    const float2 v = *reinterpret_cast<const float2*>(
        X + ((size_t)(s0 + r) * BATCH + b) * DIM + tid * 2);
    Xs[r * LDX + tid * 2] = f2bf(v.x);
    Xs[r * LDX + tid * 2 + 1] = f2bf(v.y);
  }
  wkrs[tid] = wkr[tid];
  wkrs[tid + 256] = wkr[tid + 256];
  if (tid < TS) dacc[tid] = 0.f;
  float dp0[4] = {0.f, 0.f, 0.f, 0.f};
  float dp1[4] = {0.f, 0.f, 0.f, 0.f};
  for (int et = 0; et < 8; ++et) {
    const int e0 = et * 64;
    f32x4 acc00 = {0.f,0.f,0.f,0.f}, acc01 = {0.f,0.f,0.f,0.f};
    f32x4 acc10 = {0.f,0.f,0.f,0.f}, acc11 = {0.f,0.f,0.f,0.f};
    for (int kc0 = 0; kc0 < DIM; kc0 += KC) {
      __syncthreads();
      {
        const int e = tid >> 2;
        const int kq = (tid & 3) * 16;
        const uint4* src = reinterpret_cast<const uint4*>(Mt + (size_t)(e0 + e) * DIM + kc0 + kq);
        const uint4 w0 = src[0];
        const uint4 w1 = src[1];
        *reinterpret_cast<uint4*>(&Bsh[e * LDB + kq]) = w0;
        *reinterpret_cast<uint4*>(&Bsh[e * LDB + kq + 8]) = w1;
      }
      __syncthreads();
#pragma unroll
      for (int ks = 0; ks < KC; ks += 32) {
        const int ka = kc0 + ks + 8 * g;
        const int kb = ks + 8 * g;
        const v8bf fa0 = ld8(&Xs[(32 * wr + c) * LDX + ka]);
        const v8bf fa1 = ld8(&Xs[(32 * wr + 16 + c) * LDX + ka]);
        const v8bf fb0 = ld8(&Bsh[(32 * wc + c) * LDB + kb]);
        const v8bf fb1 = ld8(&Bsh[(32 * wc + 16 + c) * LDB + kb]);
        acc00 = MFMA(fa0, fb0, acc00);
        acc01 = MFMA(fa0, fb1, acc01);
        acc10 = MFMA(fa1, fb0, acc10);
        acc11 = MFMA(fa1, fb1, acc11);
      }
    }
#pragma unroll
    for (int i = 0; i < 4; ++i) {
      const int r0 = 32 * wr + 4 * g + i;
      const int ec0 = e0 + 32 * wc + c;
      const float w0 = wkrs[ec0], w1 = wkrs[ec0 + 16];
      dp0[i] += (acc00[i] + w0) * bf2f(Xs[r0 * LDX + ec0]) +
                (acc01[i] + w1) * bf2f(Xs[r0 * LDX + ec0 + 16]);
      dp1[i] += (acc10[i] + w0) * bf2f(Xs[(r0 + 16) * LDX + ec0]) +
                (acc11[i] + w1) * bf2f(Xs[(r0 + 16) * LDX + ec0 + 16]);
    }
  }
#pragma unroll
  for (int i = 0; i < 4; ++i) {
    float v0 = dp0[i], v1 = dp1[i];
    v0 += __shfl_xor(v0, 1); v0 += __shfl_xor(v0, 2);
    v0 += __shfl_xor(v0, 4); v0 += __shfl_xor(v0, 8);
    v1 += __shfl_xor(v1, 1); v1 += __shfl_xor(v1, 2);
    v1 += __shfl_xor(v1, 4); v1 += __shfl_xor(v1, 8);
    if (c == 0) {
      atomicAdd(&dacc[32 * wr + 4 * g + i], v0);
      atomicAdd(&dacc[32 * wr + 16 + 4 * g + i], v1);
    }
  }
  __syncthreads();
  if (tid < TS) {
    float sc = dacc[tid] * SCALE;
    sc = fminf(fmaxf(sc, -5.0f), 7.0f);
    const float r = expf(sc);
    rds[tid] = r;
    rd_out[(size_t)b * SLEN + s0 + tid] = r;
    float t = r;
    t += __shfl_xor(t, 1); t += __shfl_xor(t, 2); t += __shfl_xor(t, 4);
    t += __shfl_xor(t, 8); t += __shfl_xor(t, 16); t += __shfl_xor(t, 32);
    if (tid == 0) atomicAdd(&Rsum[b], t);
  }
  __syncthreads();
#pragma unroll
  for (int dd = 0; dd < 2; ++dd) {
    const int d = tid + dd * 256;
    float s1 = 0.f, s2 = 0.f;
    for (int r = 0; r < TS; ++r) {
      const float xv = bf2f(Xs[r * LDX + d]);
      s1 += xv;
      s2 += rds[r] * xv;
    }
    atomicAdd(&xsum[(size_t)b * DIM + d], s1);
    atomicAdd(&xw[(size_t)b * DIM + d], s2);
  }
}

__global__ __launch_bounds__(256, 2) void pass2_fb(
    const float* __restrict__ X, const unsigned short* __restrict__ Wvb,
    const float* __restrict__ rd, const float* __restrict__ Rsum,
    const float* __restrict__ xsum, const float* __restrict__ xw,
    float* __restrict__ out) {
  __shared__ __align__(16) unsigned short Zs[TS * LDX];
  __shared__ __align__(16) unsigned short Bsh[64 * LDB];
  __shared__ float xss[DIM];
  __shared__ float xws[DIM];
  __shared__ float rds[TS];
  const int tid = threadIdx.x;
  const int b = blockIdx.x & 255;
  const int s0 = (blockIdx.x >> 8) * TS;
  const int lane = tid & 63;
  const int wave = tid >> 6;
  const int wr = wave >> 1, wc = wave & 1;
  const int g = lane >> 4, c = lane & 15;
  xss[tid] = xsum[(size_t)b * DIM + tid];
  xss[tid + 256] = xsum[(size_t)b * DIM + tid + 256];
  xws[tid] = xw[(size_t)b * DIM + tid];
  xws[tid + 256] = xw[(size_t)b * DIM + tid + 256];
  if (tid < TS) rds[tid] = rd[(size_t)b * SLEN + s0 + tid];
  const float Rb = Rsum[b];
  const float invR = 1.0f / Rb;
  const float gam = invR * (1.0f / 256.0f);
  __syncthreads();
#pragma unroll 4
  for (int r = 0; r < TS; ++r) {
    const float rv = rds[r];
    const float al = rv * invR - (1.0f / 256.0f);
    const float be = (1.0f - rv * invR) * (1.0f / 256.0f);
    const float2 v = *reinterpret_cast<const float2*>(
        X + ((size_t)(s0 + r) * BATCH + b) * DIM + tid * 2);
    const int d0 = tid * 2;
    Zs[r * LDX + d0] = f2bf(al * v.x + be * xss[d0] + gam * xws[d0]);
    Zs[r * LDX + d0 + 1] = f2bf(al * v.y + be * xss[d0 + 1] + gam * xws[d0 + 1]);
  }
  const size_t outbase = ((size_t)b * SLEN + s0) * DIM;
  for (int et = 0; et < 8; ++et) {
    const int e0 = et * 64;
    f32x4 acc00 = {0.f,0.f,0.f,0.f}, acc01 = {0.f,0.f,0.f,0.f};
    f32x4 acc10 = {0.f,0.f,0.f,0.f}, acc11 = {0.f,0.f,0.f,0.f};
    for (int kc0 = 0; kc0 < DIM; kc0 += KC) {
      __syncthreads();
      {
        const int e = tid >> 2;
        const int kq = (tid & 3) * 16;
        const uint4* src = reinterpret_cast<const uint4*>(Wvb + (size_t)(e0 + e) * DIM + kc0 + kq);
        const uint4 w0 = src[0];
        const uint4 w1 = src[1];
        *reinterpret_cast<uint4*>(&Bsh[e * LDB + kq]) = w0;
        *reinterpret_cast<uint4*>(&Bsh[e * LDB + kq + 8]) = w1;
      }
      __syncthreads();
#pragma unroll
      for (int ks = 0; ks < KC; ks += 32) {
        const int ka = kc0 + ks + 8 * g;
        const int kb = ks + 8 * g;
        const v8bf fa0 = ld8(&Zs[(32 * wr + c) * LDX + ka]);
        const v8bf fa1 = ld8(&Zs[(32 * wr + 16 + c) * LDX + ka]);
        const v8bf fb0 = ld8(&Bsh[(32 * wc + c) * LDB + kb]);
        const v8bf fb1 = ld8(&Bsh[(32 * wc + 16 + c) * LDB + kb]);
        acc00 = MFMA(fa0, fb0, acc00);
        acc01 = MFMA(fa0, fb1, acc01);
        acc10 = MFMA(fa1, fb0, acc10);
        acc11 = MFMA(fa1, fb1, acc11);
      }
    }
#pragma unroll
    for (int i = 0; i < 4; ++i) {
      const int r0 = 32 * wr + 4 * g + i;
      const int c0 = e0 + 32 * wc + c;
      out[outbase + (size_t)r0 * DIM + c0] = acc00[i];
      out[outbase + (size_t)r0 * DIM + c0 + 16] = acc01[i];
      out[outbase + (size_t)(r0 + 16) * DIM + c0] = acc10[i];
      out[outbase + (size_t)(r0 + 16) * DIM + c0 + 16] = acc11[i];
    }
  }
}

extern "C" void kernel_launch(void* const* d_in, const int* in_sizes, int n_in,
                              void* d_out, int out_size, void* d_ws, size_t ws_size,
                              hipStream_t stream) {
  (void)in_sizes; (void)n_in; (void)out_size;
  const float* X = (const float*)d_in[0];
  const float* Wq = (const float*)d_in[1];
  const float* Wk = (const float*)d_in[2];
  const float* Wv = (const float*)d_in[3];
  const float* rq = (const float*)d_in[4];
  float* out = (float*)d_out;
  char* ws = (char*)d_ws;

  unsigned short* Mt = (unsigned short*)(ws + 0);        // 512 KB
  unsigned short* Wvb = (unsigned short*)(ws + 524288);  // 512 KB

  const size_t NEED = 69206016;  // 2 MB headers + 64 MB Xb
  if (ws_size >= NEED) {
    float* wkr = (float*)(ws + 1048576);            // 2 KB  (plain stores)
    float* rdpart = (float*)(ws + 1052672);         // 512 KB [2][65536] (plain stores)
    unsigned short* Xb = (unsigned short*)(ws + 2097152);  // 64 MB

    prep_all<<<dim3(1538), dim3(256), 0, stream>>>(X, Wq, Wk, Wv, rq, Xb, Mt, Wvb, wkr);
    gemm1_dp<<<dim3(512), dim3(512), 0, stream>>>(Xb, Mt, wkr, rdpart);
    gemm2_f<<<dim3(512), dim3(512), 0, stream>>>(Xb, Wvb, rdpart, out);
  } else {
    // round-1 verified fallback (needs ~2.4 MB)
    float* rd = (float*)(ws + 1048576);
    float* wkr = (float*)(ws + 1310720);
    float* Rsum = (float*)(ws + 1312768);
    float* xsum = (float*)(ws + 1313792);
    float* xw = (float*)(ws + 1838080);
    zf<<<dim3(257), dim3(256), 0, stream>>>((float4*)(ws + 1310720), 65728);
    prep_mt<<<dim3(256), dim3(256), 0, stream>>>(Wq, Wk, Mt);
    conv_wv<<<dim3(256), dim3(256), 0, stream>>>(Wv, Wvb);
    wkr_k2<<<dim3(2), dim3(256), 0, stream>>>(Wk, rq, wkr);
    pass1_fb<<<dim3(1024), dim3(256), 0, stream>>>(X, Mt, wkr, rd, Rsum, xsum, xw);
    pass2_fb<<<dim3(1024), dim3(256), 0, stream>>>(X, Wvb, rd, Rsum, xsum, xw, out);
  }
}

// Round 7
// 180.615 us; speedup vs baseline: 1.4108x; 1.0353x over previous
//
#include <hip/hip_runtime.h>

typedef __bf16 v8bf __attribute__((ext_vector_type(8)));
typedef float f32x4 __attribute__((ext_vector_type(4)));
typedef unsigned short u16x8 __attribute__((ext_vector_type(8)));

#define SLEN 256
#define BATCH 256
#define DIM 512
#define SCALE 0.044194173824159216f  // sqrt(1/512)

// fallback-path tile params (round-1 verified kernels)
#define TS 64
#define LDX 520
#define LDB 72
#define KC 64

#define MFMA(a, b, c) __builtin_amdgcn_mfma_f32_16x16x32_bf16((a), (b), (c), 0, 0, 0)

__device__ __forceinline__ unsigned int f2bf(float f) {
  union { float f; unsigned int u; } v; v.f = f;
  unsigned int r = v.u + 0x7FFFu + ((v.u >> 16) & 1u);  // RNE
  return r >> 16;
}
__device__ __forceinline__ float bf2f(unsigned short u) {
  union { unsigned int u; float f; } v; v.u = ((unsigned int)u) << 16;
  return v.f;
}
__device__ __forceinline__ v8bf ld8(const unsigned short* p) {
  u16x8 t = *reinterpret_cast<const u16x8*>(p);
  return __builtin_bit_cast(v8bf, t);
}
// async global->LDS, 16B per lane; lds base must be wave-uniform
__device__ __forceinline__ void gload16(const unsigned short* g, unsigned short* l) {
  __builtin_amdgcn_global_load_lds(
      (const __attribute__((address_space(1))) unsigned int*)g,
      (__attribute__((address_space(3))) unsigned int*)l, 16, 0, 0);
}

// ---------- zf: fast zero-fill (fallback path only) ----------
__global__ __launch_bounds__(256) void zf(float4* __restrict__ p, int n4) {
  const int i = blockIdx.x * 256 + threadIdx.x;
  if (i < n4) {
    const float4 z = {0.f, 0.f, 0.f, 0.f};
    p[i] = z;
  }
}

// ---------- prep_all: small roles FIRST (dispatch order), bulk x2b last ----------
// blocks [0,256)   : prep_mt  (long-latency small grid -> must start at t=0)
// blocks [256,512) : conv_wv
// blocks [512,514) : wkr
// blocks [514,2562): x2b, 2048 blocks x 32 rows, pipelined loads + 16B stores
__global__ __launch_bounds__(256) void prep_all(const float* __restrict__ X,
                                                const float* __restrict__ Wq,
                                                const float* __restrict__ Wk,
                                                const float* __restrict__ Wv,
                                                const float* __restrict__ rq,
                                                unsigned short* __restrict__ Xb,
                                                unsigned short* __restrict__ Mt,
                                                unsigned short* __restrict__ Wvb,
                                                float* __restrict__ wkr) {
  __shared__ float As[32][33];
  __shared__ float Bs[32][33];
  const int blk = blockIdx.x;
  const int tid = threadIdx.x;

  if (blk >= 514) {
    // ---- x2b role: X[s,b,d] f32 -> Xb[b,s,d] bf16, 32 rows per block ----
    const int id = blk - 514;
    const int b = id & 255;
    const int sc = id >> 8;        // 0..7
    const int s0 = sc * 32;
    const int l = tid & 63;
    const int rg = tid >> 6;       // 0..3
    const int d0 = l * 8;          // 8 floats per lane -> full 512-col row per wave
    const size_t rstride = (size_t)4 * BATCH * DIM;  // s advances by 4 per k
    const float* xp = X + ((size_t)(s0 + rg) * BATCH + b) * DIM + d0;
    unsigned short* op = Xb + ((size_t)b * SLEN + s0 + rg) * DIM + d0;
    float4 ca = *reinterpret_cast<const float4*>(xp);
    float4 cb = *reinterpret_cast<const float4*>(xp + 4);
#pragma unroll
    for (int k = 0; k < 8; ++k) {
      float4 na, nb;
      if (k < 7) {
        const float* nx = xp + (size_t)(k + 1) * rstride;
        na = *reinterpret_cast<const float4*>(nx);
        nb = *reinterpret_cast<const float4*>(nx + 4);
      }
      uint4 pq;
      pq.x = f2bf(ca.x) | (f2bf(ca.y) << 16);
      pq.y = f2bf(ca.z) | (f2bf(ca.w) << 16);
      pq.z = f2bf(cb.x) | (f2bf(cb.y) << 16);
      pq.w = f2bf(cb.z) | (f2bf(cb.w) << 16);
      *reinterpret_cast<uint4*>(op + (size_t)k * 4 * DIM) = pq;
      ca = na; cb = nb;
    }
  } else if (blk < 256) {
    // ---- prep_mt role: Mt[e][d] = sum_f Wk[f,e]*Wq[f,d] ----
    const int e0 = (blk & 15) * 32;
    const int d0 = (blk >> 4) * 32;
    const int tm = (tid & 15) * 2;
    const int tn = (tid >> 4) * 2;
    const int lf = tid >> 3;
    const int lc = (tid & 7) * 4;
    float a00 = 0.f, a01 = 0.f, a10 = 0.f, a11 = 0.f;
    for (int f0 = 0; f0 < DIM; f0 += 32) {
      __syncthreads();
      const float4 a = *reinterpret_cast<const float4*>(Wk + (size_t)(f0 + lf) * DIM + e0 + lc);
      const float4 b = *reinterpret_cast<const float4*>(Wq + (size_t)(f0 + lf) * DIM + d0 + lc);
      As[lf][lc] = a.x; As[lf][lc + 1] = a.y; As[lf][lc + 2] = a.z; As[lf][lc + 3] = a.w;
      Bs[lf][lc] = b.x; Bs[lf][lc + 1] = b.y; Bs[lf][lc + 2] = b.z; Bs[lf][lc + 3] = b.w;
      __syncthreads();
#pragma unroll
      for (int k = 0; k < 32; ++k) {
        const float x0 = As[k][tm], x1 = As[k][tm + 1];
        const float y0 = Bs[k][tn], y1 = Bs[k][tn + 1];
        a00 += x0 * y0; a01 += x0 * y1; a10 += x1 * y0; a11 += x1 * y1;
      }
    }
    Mt[(size_t)(e0 + tm) * DIM + d0 + tn] = (unsigned short)f2bf(a00);
    Mt[(size_t)(e0 + tm) * DIM + d0 + tn + 1] = (unsigned short)f2bf(a01);
    Mt[(size_t)(e0 + tm + 1) * DIM + d0 + tn] = (unsigned short)f2bf(a10);
    Mt[(size_t)(e0 + tm + 1) * DIM + d0 + tn + 1] = (unsigned short)f2bf(a11);
  } else if (blk < 512) {
    // ---- conv_wv role ----
    const int idx = ((blk - 256) * 256 + tid) * 4;
    const float4 v = *reinterpret_cast<const float4*>(Wv + idx);
    uint2 p;
    p.x = f2bf(v.x) | (f2bf(v.y) << 16);
    p.y = f2bf(v.z) | (f2bf(v.w) << 16);
    *reinterpret_cast<uint2*>(Wvb + idx) = p;
  } else {
    // ---- wkr role (2 blocks): wkr[d] = sum_f Wk[f,d]*rq[f], plain store ----
    float* rqs = &As[0][0];  // 512 floats fits in As
    rqs[tid] = rq[tid];
    rqs[tid + 256] = rq[tid + 256];
    __syncthreads();
    const int d = (blk - 512) * 256 + tid;
    float s = 0.f;
#pragma unroll 8
    for (int f = 0; f < DIM; ++f) s += Wk[(size_t)f * DIM + d] * rqs[f];
    wkr[d] = s;
  }
}

// ============ deep-pipelined 256x256 GEMM core (BK=32, 4 LDS buffers) ============
// Verified in rounds 5/6. Swizzle: 16B granule gI at row r holds global granule
// gI ^ ((r>>1)&3); applied on pre-swizzled global source AND on ds_read.
// Counted vmcnt(8) = 2 tiles outstanding; prefetch distance 3 tiles.

#define GEMM_PROLOGUE()                                                         \
  f32x4 acc[8][4] = {};                                                         \
  STG(0); STG(1); STG(2);

#define GEMM_MAIN_LOOP()                                                        \
  for (int t = 0; t < 16; ++t) {                                                \
    if (t <= 13) { asm volatile("s_waitcnt vmcnt(8)" ::: "memory"); }           \
    else if (t == 14) { asm volatile("s_waitcnt vmcnt(4)" ::: "memory"); }      \
    else { asm volatile("s_waitcnt vmcnt(0)" ::: "memory"); }                   \
    __builtin_amdgcn_s_barrier();                                               \
    __builtin_amdgcn_sched_barrier(0);                                          \
    if (t + 3 < 16) { STG(t + 3); }                                             \
    __builtin_amdgcn_sched_barrier(0);                                          \
    const unsigned short* la = lds + (t & 3) * 16384;                           \
    const unsigned short* lb2 = la + 8192;                                      \
    v8bf a[8], bbf[4];                                                          \
    _Pragma("unroll")                                                           \
    for (int m = 0; m < 8; ++m)                                                 \
      a[m] = ld8(la + (wr * 128 + m * 16 + c) * 32 + grd);                      \
    _Pragma("unroll")                                                           \
    for (int n = 0; n < 4; ++n)                                                 \
      bbf[n] = ld8(lb2 + (wc * 64 + n * 16 + c) * 32 + grd);                    \
    __builtin_amdgcn_s_setprio(1);                                              \
    _Pragma("unroll")                                                           \
    for (int m = 0; m < 8; ++m)                                                 \
      _Pragma("unroll")                                                         \
      for (int n = 0; n < 4; ++n) acc[m][n] = MFMA(a[m], bbf[n], acc[m][n]);    \
    __builtin_amdgcn_s_setprio(0);                                              \
  }

#define STG(tt) {                                                               \
    const int kc_ = (tt) * 32;                                                  \
    unsigned short* lb_ = lw + ((tt) & 3) * 16384;                              \
    gload16(sAp + kc_, lb_);                                                    \
    gload16(sAp + kc_ + 128 * DIM, lb_ + 4096);                                 \
    gload16(sBp + kc_, lb_ + 8192);                                             \
    gload16(sBp + kc_ + 128 * DIM, lb_ + 12288); }

// ---------- gemm1: u = Xb @ Mt^T; rdpart[ct][j] = sum_e-slice (u+wkr)*x (no atomics) ----------
__global__ __launch_bounds__(512, 2) void gemm1_dp(const unsigned short* __restrict__ Xb,
                                                   const unsigned short* __restrict__ Mt,
                                                   const float* __restrict__ wkr,
                                                   float* __restrict__ rdpart) {
  __shared__ unsigned short lds[65536];  // 128 KiB
  const int tid = threadIdx.x;
  const int lane = tid & 63, w = tid >> 6;
  const int wr = w >> 2, wc = w & 3;
  const int c = lane & 15, g = lane >> 4;
  const int grd = ((g ^ ((c >> 1) & 3))) * 8;

  const int work = (blockIdx.x & 7) * 64 + (blockIdx.x >> 3);  // 512 blocks, 8 XCDs
  const int rt = work >> 1, ct = work & 1;
  const int j0 = rt * 256, e0 = ct * 256;

  const int rA = tid >> 2;
  const int gl = (tid & 3) ^ ((rA >> 1) & 3);
  const unsigned short* sAp = Xb + (size_t)(j0 + rA) * DIM + gl * 8;
  const unsigned short* sBp = Mt + (size_t)(e0 + rA) * DIM + gl * 8;
  unsigned short* lw = lds + (w << 9);

  GEMM_PROLOGUE()
  GEMM_MAIN_LOOP()

  // epilogue: per-row dot with x over this block's e-slice, LDS cross-wave combine
  __syncthreads();
  float* red = (float*)lds;  // 4 wc-slices x 256 rows
  float wkrl[4];
#pragma unroll
  for (int n = 0; n < 4; ++n) wkrl[n] = wkr[e0 + wc * 64 + n * 16 + c];
#pragma unroll
  for (int m = 0; m < 8; ++m) {
#pragma unroll
    for (int i = 0; i < 4; ++i) {
      const int rl = wr * 128 + m * 16 + 4 * g + i;
      const unsigned short* xrow = Xb + (size_t)(j0 + rl) * DIM + e0 + wc * 64 + c;
      float val = 0.f;
#pragma unroll
      for (int n = 0; n < 4; ++n)
        val += (acc[m][n][i] + wkrl[n]) * bf2f(xrow[n * 16]);
      val += __shfl_xor(val, 1); val += __shfl_xor(val, 2);
      val += __shfl_xor(val, 4); val += __shfl_xor(val, 8);
      if (c == 0) red[wc * 256 + rl] = val;
    }
  }
  __syncthreads();
  if (tid < 256) {
    const float s = red[tid] + red[256 + tid] + red[512 + tid] + red[768 + tid];
    rdpart[(size_t)ct * 65536 + j0 + tid] = s;
  }
}

// ---------- gemm2: rd/Rsum from rdpart; V = Xb @ Wvb^T; vs/vw reduced in-block;
//            out = (rd_j/R - 1/s)*V + ((1-rd_j/R)/s)*vs + (1/(sR))*vw ----------
__global__ __launch_bounds__(512, 2) void gemm2_f(const unsigned short* __restrict__ Xb,
                                                  const unsigned short* __restrict__ Wvb,
                                                  const float* __restrict__ rdpart,
                                                  float* __restrict__ out) {
  __shared__ unsigned short lds[65536];
  __shared__ float rdl[256];
  __shared__ float wsum[4];
  const int tid = threadIdx.x;
  const int lane = tid & 63, w = tid >> 6;
  const int wr = w >> 2, wc = w & 3;
  const int c = lane & 15, g = lane >> 4;
  const int grd = ((g ^ ((c >> 1) & 3))) * 8;

  const int work = (blockIdx.x & 7) * 64 + (blockIdx.x >> 3);
  const int rt = work >> 1, ct = work & 1;
  const int j0 = rt * 256, e0 = ct * 256;
  const int b = rt;  // 256-row tile == one batch

  // rd + Rsum (tiny, before any pipeline loads so __syncthreads drains nothing)
  if (tid < 256) {
    float v = (rdpart[(size_t)b * SLEN + tid] + rdpart[65536 + (size_t)b * SLEN + tid]) * SCALE;
    v = fminf(fmaxf(v, -5.0f), 7.0f);
    const float r = expf(v);
    rdl[tid] = r;
    float t = r;
    t += __shfl_xor(t, 1);  t += __shfl_xor(t, 2);  t += __shfl_xor(t, 4);
    t += __shfl_xor(t, 8);  t += __shfl_xor(t, 16); t += __shfl_xor(t, 32);
    if ((tid & 63) == 0) wsum[tid >> 6] = t;
  }
  __syncthreads();

  const int rA = tid >> 2;
  const int gl = (tid & 3) ^ ((rA >> 1) & 3);
  const unsigned short* sAp = Xb + (size_t)(j0 + rA) * DIM + gl * 8;
  const unsigned short* sBp = Wvb + (size_t)(e0 + rA) * DIM + gl * 8;
  unsigned short* lw = lds + (w << 9);

  GEMM_PROLOGUE()
  GEMM_MAIN_LOOP()

  // ---- in-block vs/vw reduction over the 256 rows (= full batch) ----
  float vsp[4] = {0.f, 0.f, 0.f, 0.f}, vwp[4] = {0.f, 0.f, 0.f, 0.f};
#pragma unroll
  for (int m = 0; m < 8; ++m) {
#pragma unroll
    for (int i = 0; i < 4; ++i) {
      const int rl = wr * 128 + m * 16 + 4 * g + i;
      const float rr = rdl[rl];
#pragma unroll
      for (int n = 0; n < 4; ++n) {
        vsp[n] += acc[m][n][i];
        vwp[n] += rr * acc[m][n][i];
      }
    }
  }
#pragma unroll
  for (int n = 0; n < 4; ++n) {
    vsp[n] += __shfl_xor(vsp[n], 16); vsp[n] += __shfl_xor(vsp[n], 32);
    vwp[n] += __shfl_xor(vwp[n], 16); vwp[n] += __shfl_xor(vwp[n], 32);
  }
  __syncthreads();  // pipeline LDS free now
  float* red = (float*)lds;  // [2][8 waves][4 n][16 c]
  if (g == 0) {
#pragma unroll
    for (int n = 0; n < 4; ++n) {
      red[(w * 4 + n) * 16 + c] = vsp[n];
      red[512 + (w * 4 + n) * 16 + c] = vwp[n];
    }
  }
  __syncthreads();
  const float Rb = wsum[0] + wsum[1] + wsum[2] + wsum[3];
  const float invR = 1.0f / Rb;
  const float gam = invR * 0.00390625f;
  const int wo = w ^ 4;  // other wr half, same wc
  float vsf[4], vwf[4];
#pragma unroll
  for (int n = 0; n < 4; ++n) {
    vsf[n] = red[(w * 4 + n) * 16 + c] + red[(wo * 4 + n) * 16 + c];
    vwf[n] = red[512 + (w * 4 + n) * 16 + c] + red[512 + (wo * 4 + n) * 16 + c];
  }
#pragma unroll
  for (int m = 0; m < 8; ++m) {
#pragma unroll
    for (int i = 0; i < 4; ++i) {
      const int rl = wr * 128 + m * 16 + 4 * g + i;
      const float tt = rdl[rl] * invR;
      const float al = tt - 0.00390625f;
      const float be = (1.0f - tt) * 0.00390625f;
      float* orow = out + (size_t)(j0 + rl) * DIM + e0 + wc * 64 + c;
#pragma unroll
      for (int n = 0; n < 4; ++n)
        orow[n * 16] = al * acc[m][n][i] + be * vsf[n] + gam * vwf[n];
    }
  }
}

// =================== fallback prep kernels (round-1 verified) ===================
__global__ __launch_bounds__(256) void prep_mt(const float* __restrict__ Wq,
                                               const float* __restrict__ Wk,
                                               unsigned short* __restrict__ Mt) {
  __shared__ float As[32][33];
  __shared__ float Bs[32][33];
  const int e0 = (blockIdx.x & 15) * 32;
  const int d0 = (blockIdx.x >> 4) * 32;
  const int tid = threadIdx.x;
  const int tm = (tid & 15) * 2;
  const int tn = (tid >> 4) * 2;
  const int lf = tid >> 3;
  const int lc = (tid & 7) * 4;
  float a00 = 0.f, a01 = 0.f, a10 = 0.f, a11 = 0.f;
  for (int f0 = 0; f0 < DIM; f0 += 32) {
    __syncthreads();
    const float4 a = *reinterpret_cast<const float4*>(Wk + (size_t)(f0 + lf) * DIM + e0 + lc);
    const float4 b = *reinterpret_cast<const float4*>(Wq + (size_t)(f0 + lf) * DIM + d0 + lc);
    As[lf][lc] = a.x; As[lf][lc + 1] = a.y; As[lf][lc + 2] = a.z; As[lf][lc + 3] = a.w;
    Bs[lf][lc] = b.x; Bs[lf][lc + 1] = b.y; Bs[lf][lc + 2] = b.z; Bs[lf][lc + 3] = b.w;
    __syncthreads();
#pragma unroll
    for (int k = 0; k < 32; ++k) {
      const float x0 = As[k][tm], x1 = As[k][tm + 1];
      const float y0 = Bs[k][tn], y1 = Bs[k][tn + 1];
      a00 += x0 * y0; a01 += x0 * y1; a10 += x1 * y0; a11 += x1 * y1;
    }
  }
  Mt[(size_t)(e0 + tm) * DIM + d0 + tn] = (unsigned short)f2bf(a00);
  Mt[(size_t)(e0 + tm) * DIM + d0 + tn + 1] = (unsigned short)f2bf(a01);
  Mt[(size_t)(e0 + tm + 1) * DIM + d0 + tn] = (unsigned short)f2bf(a10);
  Mt[(size_t)(e0 + tm + 1) * DIM + d0 + tn + 1] = (unsigned short)f2bf(a11);
}

__global__ __launch_bounds__(256) void conv_wv(const float* __restrict__ Wv,
                                               unsigned short* __restrict__ Wvb) {
  const int idx = (blockIdx.x * 256 + threadIdx.x) * 4;
  const float4 v = *reinterpret_cast<const float4*>(Wv + idx);
  uint2 p;
  p.x = f2bf(v.x) | (f2bf(v.y) << 16);
  p.y = f2bf(v.z) | (f2bf(v.w) << 16);
  *reinterpret_cast<uint2*>(Wvb + idx) = p;
}

__global__ __launch_bounds__(256) void wkr_k2(const float* __restrict__ Wk,
                                              const float* __restrict__ rq,
                                              float* __restrict__ wkr) {
  __shared__ float rqs[DIM];
  const int tid = threadIdx.x;
  rqs[tid] = rq[tid];
  rqs[tid + 256] = rq[tid + 256];
  __syncthreads();
  const int d = blockIdx.x * 256 + tid;
  float s = 0.f;
#pragma unroll 8
  for (int f = 0; f < DIM; ++f) s += Wk[(size_t)f * DIM + d] * rqs[f];
  wkr[d] = s;
}

// =================== round-1 fallback main kernels (verified) ===================
__global__ __launch_bounds__(256, 2) void pass1_fb(
    const float* __restrict__ X, const unsigned short* __restrict__ Mt,
    const float* __restrict__ wkr, float* __restrict__ rd_out,
    float* __restrict__ Rsum, float* __restrict__ xsum, float* __restrict__ xw) {
  __shared__ __align__(16) unsigned short Xs[TS * LDX];
  __shared__ __align__(16) unsigned short Bsh[64 * LDB];
  __shared__ float wkrs[DIM];
  __shared__ float dacc[TS];
  __shared__ float rds[TS];
  const int tid = threadIdx.x;
  const int b = blockIdx.x & 255;
  const int s0 = (blockIdx.x >> 8) * TS;
  const int lane = tid & 63;
  const int wave = tid >> 6;
  const int wr = wave >> 1, wc = wave & 1;
  const int g = lane >> 4, c = lane & 15;
#pragma unroll 4
  for (int r = 0; r < TS; ++r) {
    const float2 v = *reinterpret_cast<const float2*>(
        X + ((size_t)(s0 + r) * BATCH + b) * DIM + tid * 2);
    Xs[r * LDX + tid * 2] = (unsigned short)f2bf(v.x);
    Xs[r * LDX + tid * 2 + 1] = (unsigned short)f2bf(v.y);
  }
  wkrs[tid] = wkr[tid];
  wkrs[tid + 256] = wkr[tid + 256];
  if (tid < TS) dacc[tid] = 0.f;
  float dp0[4] = {0.f, 0.f, 0.f, 0.f};
  float dp1[4] = {0.f, 0.f, 0.f, 0.f};
  for (int et = 0; et < 8; ++et) {
    const int e0 = et * 64;
    f32x4 acc00 = {0.f,0.f,0.f,0.f}, acc01 = {0.f,0.f,0.f,0.f};
    f32x4 acc10 = {0.f,0.f,0.f,0.f}, acc11 = {0.f,0.f,0.f,0.f};
    for (int kc0 = 0; kc0 < DIM; kc0 += KC) {
      __syncthreads();
      {
        const int e = tid >> 2;
        const int kq = (tid & 3) * 16;
        const uint4* src = reinterpret_cast<const uint4*>(Mt + (size_t)(e0 + e) * DIM + kc0 + kq);
        const uint4 w0 = src[0];
        const uint4 w1 = src[1];
        *reinterpret_cast<uint4*>(&Bsh[e * LDB + kq]) = w0;
        *reinterpret_cast<uint4*>(&Bsh[e * LDB + kq + 8]) = w1;
      }
      __syncthreads();
#pragma unroll
      for (int ks = 0; ks < KC; ks += 32) {
        const int ka = kc0 + ks + 8 * g;
        const int kb = ks + 8 * g;
        const v8bf fa0 = ld8(&Xs[(32 * wr + c) * LDX + ka]);
        const v8bf fa1 = ld8(&Xs[(32 * wr + 16 + c) * LDX + ka]);
        const v8bf fb0 = ld8(&Bsh[(32 * wc + c) * LDB + kb]);
        const v8bf fb1 = ld8(&Bsh[(32 * wc + 16 + c) * LDB + kb]);
        acc00 = MFMA(fa0, fb0, acc00);
        acc01 = MFMA(fa0, fb1, acc01);
        acc10 = MFMA(fa1, fb0, acc10);
        acc11 = MFMA(fa1, fb1, acc11);
      }
    }
#pragma unroll
    for (int i = 0; i < 4; ++i) {
      const int r0 = 32 * wr + 4 * g + i;
      const int ec0 = e0 + 32 * wc + c;
      const float w0 = wkrs[ec0], w1 = wkrs[ec0 + 16];
      dp0[i] += (acc00[i] + w0) * bf2f(Xs[r0 * LDX + ec0]) +
                (acc01[i] + w1) * bf2f(Xs[r0 * LDX + ec0 + 16]);
      dp1[i] += (acc10[i] + w0) * bf2f(Xs[(r0 + 16) * LDX + ec0]) +
                (acc11[i] + w1) * bf2f(Xs[(r0 + 16) * LDX + ec0 + 16]);
    }
  }
#pragma unroll
  for (int i = 0; i < 4; ++i) {
    float v0 = dp0[i], v1 = dp1[i];
    v0 += __shfl_xor(v0, 1); v0 += __shfl_xor(v0, 2);
    v0 += __shfl_xor(v0, 4); v0 += __shfl_xor(v0, 8);
    v1 += __shfl_xor(v1, 1); v1 += __shfl_xor(v1, 2);
    v1 += __shfl_xor(v1, 4); v1 += __shfl_xor(v1, 8);
    if (c == 0) {
      atomicAdd(&dacc[32 * wr + 4 * g + i], v0);
      atomicAdd(&dacc[32 * wr + 16 + 4 * g + i], v1);
    }
  }
  __syncthreads();
  if (tid < TS) {
    float sc = dacc[tid] * SCALE;
    sc = fminf(fmaxf(sc, -5.0f), 7.0f);
    const float r = expf(sc);
    rds[tid] = r;
    rd_out[(size_t)b * SLEN + s0 + tid] = r;
    float t = r;
    t += __shfl_xor(t, 1); t += __shfl_xor(t, 2); t += __shfl_xor(t, 4);
    t += __shfl_xor(t, 8); t += __shfl_xor(t, 16); t += __shfl_xor(t, 32);
    if (tid == 0) atomicAdd(&Rsum[b], t);
  }
  __syncthreads();
#pragma unroll
  for (int dd = 0; dd < 2; ++dd) {
    const int d = tid + dd * 256;
    float s1 = 0.f, s2 = 0.f;
    for (int r = 0; r < TS; ++r) {
      const float xv = bf2f(Xs[r * LDX + d]);
      s1 += xv;
      s2 += rds[r] * xv;
    }
    atomicAdd(&xsum[(size_t)b * DIM + d], s1);
    atomicAdd(&xw[(size_t)b * DIM + d], s2);
  }
}

__global__ __launch_bounds__(256, 2) void pass2_fb(
    const float* __restrict__ X, const unsigned short* __restrict__ Wvb,
    const float* __restrict__ rd, const float* __restrict__ Rsum,
    const float* __restrict__ xsum, const float* __restrict__ xw,
    float* __restrict__ out) {
  __shared__ __align__(16) unsigned short Zs[TS * LDX];
  __shared__ __align__(16) unsigned short Bsh[64 * LDB];
  __shared__ float xss[DIM];
  __shared__ float xws[DIM];
  __shared__ float rds[TS];
  const int tid = threadIdx.x;
  const int b = blockIdx.x & 255;
  const int s0 = (blockIdx.x >> 8) * TS;
  const int lane = tid & 63;
  const int wave = tid >> 6;
  const int wr = wave >> 1, wc = wave & 1;
  const int g = lane >> 4, c = lane & 15;
  xss[tid] = xsum[(size_t)b * DIM + tid];
  xss[tid + 256] = xsum[(size_t)b * DIM + tid + 256];
  xws[tid] = xw[(size_t)b * DIM + tid];
  xws[tid + 256] = xw[(size_t)b * DIM + tid + 256];
  if (tid < TS) rds[tid] = rd[(size_t)b * SLEN + s0 + tid];
  const float Rb = Rsum[b];
  const float invR = 1.0f / Rb;
  const float gam = invR * (1.0f / 256.0f);
  __syncthreads();
#pragma unroll 4
  for (int r = 0; r < TS; ++r) {
    const float rv = rds[r];
    const float al = rv * invR - (1.0f / 256.0f);
    const float be = (1.0f - rv * invR) * (1.0f / 256.0f);
    const float2 v = *reinterpret_cast<const float2*>(
        X + ((size_t)(s0 + r) * BATCH + b) * DIM + tid * 2);
    const int d0 = tid * 2;
    Zs[r * LDX + d0] = (unsigned short)f2bf(al * v.x + be * xss[d0] + gam * xws[d0]);
    Zs[r * LDX + d0 + 1] = (unsigned short)f2bf(al * v.y + be * xss[d0 + 1] + gam * xws[d0 + 1]);
  }
  const size_t outbase = ((size_t)b * SLEN + s0) * DIM;
  for (int et = 0; et < 8; ++et) {
    const int e0 = et * 64;
    f32x4 acc00 = {0.f,0.f,0.f,0.f}, acc01 = {0.f,0.f,0.f,0.f};
    f32x4 acc10 = {0.f,0.f,0.f,0.f}, acc11 = {0.f,0.f,0.f,0.f};
    for (int kc0 = 0; kc0 < DIM; kc0 += KC) {
      __syncthreads();
      {
        const int e = tid >> 2;
        const int kq = (tid & 3) * 16;
        const uint4* src = reinterpret_cast<const uint4*>(Wvb + (size_t)(e0 + e) * DIM + kc0 + kq);
        const uint4 w0 = src[0];
        const uint4 w1 = src[1];
        *reinterpret_cast<uint4*>(&Bsh[e * LDB + kq]) = w0;
        *reinterpret_cast<uint4*>(&Bsh[e * LDB + kq + 8]) = w1;
      }
      __syncthreads();
#pragma unroll
      for (int ks = 0; ks < KC; ks += 32) {
        const int ka = kc0 + ks + 8 * g;
        const int kb = ks + 8 * g;
        const v8bf fa0 = ld8(&Zs[(32 * wr + c) * LDX + ka]);
        const v8bf fa1 = ld8(&Zs[(32 * wr + 16 + c) * LDX + ka]);
        const v8bf fb0 = ld8(&Bsh[(32 * wc + c) * LDB + kb]);
        const v8bf fb1 = ld8(&Bsh[(32 * wc + 16 + c) * LDB + kb]);
        acc00 = MFMA(fa0, fb0, acc00);
        acc01 = MFMA(fa0, fb1, acc01);
        acc10 = MFMA(fa1, fb0, acc10);
        acc11 = MFMA(fa1, fb1, acc11);
      }
    }
#pragma unroll
    for (int i = 0; i < 4; ++i) {
      const int r0 = 32 * wr + 4 * g + i;
      const int c0 = e0 + 32 * wc + c;
      out[outbase + (size_t)r0 * DIM + c0] = acc00[i];
      out[outbase + (size_t)r0 * DIM + c0 + 16] = acc01[i];
      out[outbase + (size_t)(r0 + 16) * DIM + c0] = acc10[i];
      out[outbase + (size_t)(r0 + 16) * DIM + c0 + 16] = acc11[i];
    }
  }
}

extern "C" void kernel_launch(void* const* d_in, const int* in_sizes, int n_in,
                              void* d_out, int out_size, void* d_ws, size_t ws_size,
                              hipStream_t stream) {
  (void)in_sizes; (void)n_in; (void)out_size;
  const float* X = (const float*)d_in[0];
  const float* Wq = (const float*)d_in[1];
  const float* Wk = (const float*)d_in[2];
  const float* Wv = (const float*)d_in[3];
  const float* rq = (const float*)d_in[4];
  float* out = (float*)d_out;
  char* ws = (char*)d_ws;

  unsigned short* Mt = (unsigned short*)(ws + 0);        // 512 KB
  unsigned short* Wvb = (unsigned short*)(ws + 524288);  // 512 KB

  const size_t NEED = 69206016;  // 2 MB headers + 64 MB Xb
  if (ws_size >= NEED) {
    float* wkr = (float*)(ws + 1048576);            // 2 KB  (plain stores)
    float* rdpart = (float*)(ws + 1052672);         // 512 KB [2][65536] (plain stores)
    unsigned short* Xb = (unsigned short*)(ws + 2097152);  // 64 MB

    prep_all<<<dim3(2562), dim3(256), 0, stream>>>(X, Wq, Wk, Wv, rq, Xb, Mt, Wvb, wkr);
    gemm1_dp<<<dim3(512), dim3(512), 0, stream>>>(Xb, Mt, wkr, rdpart);
    gemm2_f<<<dim3(512), dim3(512), 0, stream>>>(Xb, Wvb, rdpart, out);
  } else {
    // round-1 verified fallback (needs ~2.4 MB)
    float* rd = (float*)(ws + 1048576);
    float* wkr = (float*)(ws + 1310720);
    float* Rsum = (float*)(ws + 1312768);
    float* xsum = (float*)(ws + 1313792);
    float* xw = (float*)(ws + 1838080);
    zf<<<dim3(257), dim3(256), 0, stream>>>((float4*)(ws + 1310720), 65728);
    prep_mt<<<dim3(256), dim3(256), 0, stream>>>(Wq, Wk, Mt);
    conv_wv<<<dim3(256), dim3(256), 0, stream>>>(Wv, Wvb);
    wkr_k2<<<dim3(2), dim3(256), 0, stream>>>(Wk, rq, wkr);
    pass1_fb<<<dim3(1024), dim3(256), 0, stream>>>(X, Mt, wkr, rd, Rsum, xsum, xw);
    pass2_fb<<<dim3(1024), dim3(256), 0, stream>>>(X, Wvb, rd, Rsum, xsum, xw, out);
  }
}